// Round 5
// baseline (431.049 us; speedup 1.0000x reference)
//
#include <hip/hip_runtime.h>
#include <math.h>

#define IMG 4320
#define H2D 2160
#define FMD 1080
#define FF 21

// ---------------- workspace layout (float units) ----------------
#define H2_OFF    0                       // 2*2160*2160 = 9331200
#define RED_OFF   9331200                 // 1080*1080   = 1166400
#define Y_OFF     10497600                // 2*21*21     = 882
#define PROPS_OFF 10498482                // 20
#define RECTS_OFF 10498502                // 80 ints
#define POOL_OFF  10498582                // 20 uints

// ============================================================================
// K1: conv1 -> conv2 -> maxpool2  (x -> h2 [2,2160,2160])
// Thread = one pooled column (ox), band of 8 pooled rows. Streams c1 rows;
// each c1 row is computed from 27 fresh float2 loads (lane-stride 8B =
// perfectly coalesced) and consumed immediately into accA/accB conv2
// accumulators. No LDS, no shfl, no cross-iteration register windows.
// ============================================================================

template<bool EX>
__device__ __forceinline__ void k1_c1row(
    const int R, const int ox, const bool okL, const bool okR,
    const float* __restrict__ x, const float* __restrict__ w1,
    const float* __restrict__ b1, float (&C1)[3][4]) {
  float xv[3][3][6];
  #pragma unroll
  for (int p = 0; p < 3; ++p) {
    const float* plane = x + (size_t)p * IMG * IMG;
    #pragma unroll
    for (int ry = 0; ry < 3; ++ry) {
      const int row = R - 1 + ry;
      if ((unsigned)row < (unsigned)IMG) {   // wave-uniform branch
        const float2* rp = (const float2*)(plane + (size_t)row * IMG);
        float2 a = rp[EX ? (okL ? ox - 1 : ox) : (ox - 1)];
        const float2 b = rp[ox];
        float2 c = rp[EX ? (okR ? ox + 1 : ox) : (ox + 1)];
        if (EX) {
          a.x = okL ? a.x : 0.f; a.y = okL ? a.y : 0.f;
          c.x = okR ? c.x : 0.f; c.y = okR ? c.y : 0.f;
        }
        xv[p][ry][0] = a.x; xv[p][ry][1] = a.y;
        xv[p][ry][2] = b.x; xv[p][ry][3] = b.y;
        xv[p][ry][4] = c.x; xv[p][ry][5] = c.y;
      } else {
        #pragma unroll
        for (int k = 0; k < 6; ++k) xv[p][ry][k] = 0.f;
      }
    }
  }
  #pragma unroll
  for (int q = 0; q < 3; ++q) {
    const float bq = b1[q];
    #pragma unroll
    for (int j = 0; j < 4; ++j) C1[q][j] = bq;
  }
  #pragma unroll
  for (int p = 0; p < 3; ++p)
    #pragma unroll
    for (int ry = 0; ry < 3; ++ry)
      #pragma unroll
      for (int dx = 0; dx < 3; ++dx)
        #pragma unroll
        for (int q = 0; q < 3; ++q) {
          const float w = w1[q * 27 + p * 9 + ry * 3 + dx];
          #pragma unroll
          for (int j = 0; j < 4; ++j) C1[q][j] += xv[p][ry][j + dx] * w;
        }
  if (EX) {
    #pragma unroll
    for (int q = 0; q < 3; ++q) {
      C1[q][0] = okL ? C1[q][0] : 0.f;   // c1 col 2ox-1 invalid at ox=0
      C1[q][3] = okR ? C1[q][3] : 0.f;   // c1 col 2ox+2 invalid at ox=2159
    }
  }
}

template<int S, int DY>
__device__ __forceinline__ void k1_contrib(float (&A)[2][2][2],
    const float (&C1)[3][4], const float* __restrict__ w2) {
  #pragma unroll
  for (int oc = 0; oc < 2; ++oc)
    #pragma unroll
    for (int cc = 0; cc < 2; ++cc) {
      float t = 0.f;
      #pragma unroll
      for (int q = 0; q < 3; ++q)
        #pragma unroll
        for (int dx = 0; dx < 3; ++dx)
          t += C1[q][cc + dx] * w2[oc * 27 + q * 9 + DY * 3 + dx];
      A[oc][S][cc] += t;
    }
}

template<bool EX>
__device__ __forceinline__ void k1_body(const int ox, const int band,
    const float* __restrict__ x,
    const float* __restrict__ w1, const float* __restrict__ b1,
    const float* __restrict__ w2, const float* __restrict__ b2,
    float* __restrict__ h2) {
  const bool okL = ox >= 1, okR = ox <= H2D - 2;
  const int oy0 = band * 8;
  float accA[2][2][2], accB[2][2][2];
  #pragma unroll
  for (int oc = 0; oc < 2; ++oc) {
    const float bb = b2[oc];
    #pragma unroll
    for (int s = 0; s < 2; ++s)
      #pragma unroll
      for (int cc = 0; cc < 2; ++cc) { accA[oc][s][cc] = bb; accB[oc][s][cc] = bb; }
  }
  {
    float C1[3][4];
    const int Ra = 2 * oy0 - 1;
    if (Ra >= 0) {                         // false only for band 0 (uniform)
      k1_c1row<EX>(Ra, ox, okL, okR, x, w1, b1, C1);
      k1_contrib<0, 0>(accA, C1, w2);
    }
    k1_c1row<EX>(2 * oy0, ox, okL, okR, x, w1, b1, C1);
    k1_contrib<0, 1>(accA, C1, w2);
    k1_contrib<1, 0>(accA, C1, w2);
  }
  #pragma unroll 1
  for (int py = 0; py < 8; ++py) {
    const int oy = oy0 + py;
    float C1[3][4];
    k1_c1row<EX>(2 * oy + 1, ox, okL, okR, x, w1, b1, C1);
    k1_contrib<0, 2>(accA, C1, w2);
    k1_contrib<1, 1>(accA, C1, w2);
    k1_contrib<0, 0>(accB, C1, w2);
    const int R2 = 2 * oy + 2;
    if (R2 < IMG) {                        // false only band 269, py 7 (uniform)
      k1_c1row<EX>(R2, ox, okL, okR, x, w1, b1, C1);
      k1_contrib<1, 2>(accA, C1, w2);
      k1_contrib<0, 1>(accB, C1, w2);
      k1_contrib<1, 0>(accB, C1, w2);
    }
    #pragma unroll
    for (int oc = 0; oc < 2; ++oc) {
      const float m = fmaxf(fmaxf(accA[oc][0][0], accA[oc][0][1]),
                            fmaxf(accA[oc][1][0], accA[oc][1][1]));
      h2[(size_t)oc * H2D * H2D + (size_t)oy * H2D + ox] = m;
      const float bb = b2[oc];
      #pragma unroll
      for (int s = 0; s < 2; ++s)
        #pragma unroll
        for (int cc = 0; cc < 2; ++cc) {
          accA[oc][s][cc] = accB[oc][s][cc];
          accB[oc][s][cc] = bb;
        }
    }
  }
}

__global__ __launch_bounds__(256) void k1_colstream(
    const float* __restrict__ x,
    const float* __restrict__ w1, const float* __restrict__ b1,
    const float* __restrict__ w2, const float* __restrict__ b2,
    float* __restrict__ h2) {
  const int ox = blockIdx.x * 256 + threadIdx.x;
  if (ox >= H2D) return;
  const bool ex = (blockIdx.x == 0) || (blockIdx.x == gridDim.x - 1);
  if (ex) k1_body<true >(ox, blockIdx.y, x, w1, b1, w2, b2, h2);
  else    k1_body<false>(ox, blockIdx.y, x, w1, b1, w2, b2, h2);
}

// ============================================================================
// K2: conv3 -> conv4 -> maxpool2  (h2 -> reduced [1080,1080]), same structure
// ============================================================================

template<bool EX>
__device__ __forceinline__ void k2_c3row(
    const int R, const int ox, const bool okL, const bool okR,
    const float* __restrict__ h2, const float* __restrict__ w3,
    const float* __restrict__ b3, float (&C3)[2][4]) {
  float xv[2][3][6];
  #pragma unroll
  for (int p = 0; p < 2; ++p) {
    const float* plane = h2 + (size_t)p * H2D * H2D;
    #pragma unroll
    for (int ry = 0; ry < 3; ++ry) {
      const int row = R - 1 + ry;
      if ((unsigned)row < (unsigned)H2D) {
        const float2* rp = (const float2*)(plane + (size_t)row * H2D);
        float2 a = rp[EX ? (okL ? ox - 1 : ox) : (ox - 1)];
        const float2 b = rp[ox];
        float2 c = rp[EX ? (okR ? ox + 1 : ox) : (ox + 1)];
        if (EX) {
          a.x = okL ? a.x : 0.f; a.y = okL ? a.y : 0.f;
          c.x = okR ? c.x : 0.f; c.y = okR ? c.y : 0.f;
        }
        xv[p][ry][0] = a.x; xv[p][ry][1] = a.y;
        xv[p][ry][2] = b.x; xv[p][ry][3] = b.y;
        xv[p][ry][4] = c.x; xv[p][ry][5] = c.y;
      } else {
        #pragma unroll
        for (int k = 0; k < 6; ++k) xv[p][ry][k] = 0.f;
      }
    }
  }
  #pragma unroll
  for (int q = 0; q < 2; ++q) {
    const float bq = b3[q];
    #pragma unroll
    for (int j = 0; j < 4; ++j) C3[q][j] = bq;
  }
  #pragma unroll
  for (int p = 0; p < 2; ++p)
    #pragma unroll
    for (int ry = 0; ry < 3; ++ry)
      #pragma unroll
      for (int dx = 0; dx < 3; ++dx)
        #pragma unroll
        for (int q = 0; q < 2; ++q) {
          const float w = w3[q * 18 + p * 9 + ry * 3 + dx];
          #pragma unroll
          for (int j = 0; j < 4; ++j) C3[q][j] += xv[p][ry][j + dx] * w;
        }
  if (EX) {
    #pragma unroll
    for (int q = 0; q < 2; ++q) {
      C3[q][0] = okL ? C3[q][0] : 0.f;
      C3[q][3] = okR ? C3[q][3] : 0.f;
    }
  }
}

template<int S, int DY>
__device__ __forceinline__ void k2_contrib(float (&A)[2][2],
    const float (&C3)[2][4], const float* __restrict__ w4) {
  #pragma unroll
  for (int cc = 0; cc < 2; ++cc) {
    float t = 0.f;
    #pragma unroll
    for (int q = 0; q < 2; ++q)
      #pragma unroll
      for (int dx = 0; dx < 3; ++dx)
        t += C3[q][cc + dx] * w4[q * 9 + DY * 3 + dx];
    A[S][cc] += t;
  }
}

template<bool EX>
__device__ __forceinline__ void k2_body(const int ox, const int band,
    const float* __restrict__ h2,
    const float* __restrict__ w3, const float* __restrict__ b3,
    const float* __restrict__ w4, const float* __restrict__ b4,
    float* __restrict__ red) {
  const bool okL = ox >= 1, okR = ox <= FMD - 2;
  const int oy0 = band * 4;
  const float bb = b4[0];
  float accA[2][2], accB[2][2];
  #pragma unroll
  for (int s = 0; s < 2; ++s)
    #pragma unroll
    for (int cc = 0; cc < 2; ++cc) { accA[s][cc] = bb; accB[s][cc] = bb; }
  {
    float C3[2][4];
    const int Ra = 2 * oy0 - 1;
    if (Ra >= 0) {
      k2_c3row<EX>(Ra, ox, okL, okR, h2, w3, b3, C3);
      k2_contrib<0, 0>(accA, C3, w4);
    }
    k2_c3row<EX>(2 * oy0, ox, okL, okR, h2, w3, b3, C3);
    k2_contrib<0, 1>(accA, C3, w4);
    k2_contrib<1, 0>(accA, C3, w4);
  }
  #pragma unroll 1
  for (int py = 0; py < 4; ++py) {
    const int oy = oy0 + py;
    float C3[2][4];
    k2_c3row<EX>(2 * oy + 1, ox, okL, okR, h2, w3, b3, C3);
    k2_contrib<0, 2>(accA, C3, w4);
    k2_contrib<1, 1>(accA, C3, w4);
    k2_contrib<0, 0>(accB, C3, w4);
    const int R2 = 2 * oy + 2;
    if (R2 < H2D) {
      k2_c3row<EX>(R2, ox, okL, okR, h2, w3, b3, C3);
      k2_contrib<1, 2>(accA, C3, w4);
      k2_contrib<0, 1>(accB, C3, w4);
      k2_contrib<1, 0>(accB, C3, w4);
    }
    const float m = fmaxf(fmaxf(accA[0][0], accA[0][1]),
                          fmaxf(accA[1][0], accA[1][1]));
    red[(size_t)oy * FMD + ox] = m;
    #pragma unroll
    for (int s = 0; s < 2; ++s)
      #pragma unroll
      for (int cc = 0; cc < 2; ++cc) {
        accA[s][cc] = accB[s][cc];
        accB[s][cc] = bb;
      }
  }
}

__global__ __launch_bounds__(256) void k2_colstream(
    const float* __restrict__ h2,
    const float* __restrict__ w3, const float* __restrict__ b3,
    const float* __restrict__ w4, const float* __restrict__ b4,
    float* __restrict__ red) {
  const int ox = blockIdx.x * 256 + threadIdx.x;
  if (ox >= FMD) return;
  const bool ex = (blockIdx.x == 0) || (blockIdx.x == gridDim.x - 1);
  if (ex) k2_body<true >(ox, blockIdx.y, h2, w3, b3, w4, b4, red);
  else    k2_body<false>(ox, blockIdx.y, h2, w3, b3, w4, b4, red);
}

// ============ K3: rpn_conv (50x50, stride 50)  (reduced -> y [2,21,21]) ============
__global__ __launch_bounds__(256) void k3_rpnconv(
    const float* __restrict__ red,
    const float* __restrict__ w, const float* __restrict__ b,
    float* __restrict__ y) {
  __shared__ float part[256];
  const int cell = blockIdx.x;
  const int i = cell / FF, j = cell % FF;
  const int tid = threadIdx.x;
  float a0 = 0.f, a1 = 0.f;
  for (int t = tid; t < 2500; t += 256) {
    int ay = t / 50, ax = t % 50;
    float v = red[(size_t)(50 * i + ay) * FMD + 50 * j + ax];
    a0 += v * w[t];
    a1 += v * w[2500 + t];
  }
  part[tid] = a0;
  __syncthreads();
  for (int s = 128; s > 0; s >>= 1) {
    if (tid < s) part[tid] += part[tid + s];
    __syncthreads();
  }
  if (tid == 0) y[cell] = part[0] + b[0];
  __syncthreads();
  part[tid] = a1;
  __syncthreads();
  for (int s = 128; s > 0; s >>= 1) {
    if (tid < s) part[tid] += part[tid + s];
    __syncthreads();
  }
  if (tid == 0) y[441 + cell] = part[0] + b[1];
}

// ============ K4: rpn heads, selection (faithful masked-select bug),
//               proposals, RoI rects, pooled-init ============
__global__ __launch_bounds__(512) void k4_select(
    const float* __restrict__ y,
    const float* __restrict__ bbw, const float* __restrict__ bbb,
    const float* __restrict__ clw, const float* __restrict__ clb,
    float* __restrict__ props_out, int* __restrict__ rects,
    unsigned* __restrict__ pooled_m) {
  __shared__ float ys[2][23][23];
  __shared__ unsigned char flag[6][441];
  __shared__ short pos[6][20];
  __shared__ int cnt[6];
  __shared__ int selT[20];
  __shared__ float offv[20], anchv[20];
  const int tid = threadIdx.x;
  for (int l = tid; l < 2 * 23 * 23; l += 512) ((float*)ys)[l] = 0.f;
  __syncthreads();
  for (int l = tid; l < 2 * 441; l += 512) {
    int c = l / 441, p = l % 441;
    ys[c][p / 21 + 1][p % 21 + 1] = y[l];
  }
  __syncthreads();
  for (int l = tid; l < 6 * 441; l += 512) {
    int a = l / 441, p = l % 441, i = p / 21, j = p % 21;
    float v = clb[a];
    #pragma unroll
    for (int c2 = 0; c2 < 2; c2++)
      #pragma unroll
      for (int dy = 0; dy < 3; dy++)
        #pragma unroll
        for (int dx = 0; dx < 3; dx++)
          v += ys[c2][i + dy][j + dx] * clw[a * 18 + c2 * 9 + dy * 3 + dx];
    flag[a][p] = (tanhf(v) > 0.95f) ? 1 : 0;
  }
  __syncthreads();
  if (tid < 6) {
    int c = 0;
    for (int p = 0; p < 441; p++)
      if (flag[tid][p]) {
        if (c < 20) pos[tid][c] = (short)p;
        c++;
      }
    cnt[tid] = c;
  }
  __syncthreads();
  if (tid == 0) {
    int s = 0;
    for (int g = 0; g < 24 && s < 20; g++) {
      int a = g >> 2;
      int take = cnt[a] < 20 - s ? cnt[a] : 20 - s;
      for (int r = 0; r < take; r++) selT[s++] = g * 441 + (int)pos[a][r];
    }
    if (s < 20) {
      for (int t = 0; t < 10584 && s < 20; t++) {
        int a = t / 1764, p = t % 441;
        if (!flag[a][p]) selT[s++] = t;
      }
    }
  }
  __syncthreads();
  if (tid < 20) {
    int t = selT[tid];
    int ch = t / 441, p = t % 441, i = p / 21, j = p % 21;
    int a = ch >> 2, c = ch & 3;
    float v = bbb[ch];
    #pragma unroll
    for (int c2 = 0; c2 < 2; c2++)
      #pragma unroll
      for (int dy = 0; dy < 3; dy++)
        #pragma unroll
        for (int dx = 0; dx < 3; dx++)
          v += ys[c2][i + dy][j + dx] * bbw[ch * 18 + c2 * 9 + dy * 3 + dx];
    offv[tid] = v;
    float sz = (a < 3) ? 1.f : 2.f;
    int am = a % 3;
    float ar = (am == 0) ? 0.5f : (am == 1 ? 1.f : 2.f);
    float base;
    if (c == 0) base = 0.f;
    else if (c == 1) base = sz * -(ar - 1.f) * 0.5f;
    else if (c == 2) base = sz;
    else base = sz * (1.f + (ar - 1.f) * 0.5f);
    anchv[tid] = base + ((c & 1) ? (float)j : (float)i);
  }
  __syncthreads();
  if (tid < 5) {
    int k = tid;
    float o0 = offv[4 * k], o1 = offv[4 * k + 1], o2 = offv[4 * k + 2], o3 = offv[4 * k + 3];
    float a0 = anchv[4 * k], a2 = anchv[4 * k + 2], a3 = anchv[4 * k + 3];
    float p0 = fminf(fmaxf(o0 + a0 - a2 * 0.5f, 0.f), 21.f) * 50.f;
    float p1 = fminf(fmaxf(o1 - a3 * 0.5f, 0.f), 21.f) * 50.f;
    float p2 = fminf(fmaxf(o2 + a0 + a2 * 0.5f, 0.f), 21.f) * 50.f;
    float p3 = fminf(fmaxf(o3 + a3 * 0.5f, 0.f), 21.f) * 50.f;
    props_out[k * 4 + 0] = p0;
    props_out[k * 4 + 1] = p1;
    props_out[k * 4 + 2] = p2;
    props_out[k * 4 + 3] = p3;
    float x1 = rintf(p0), y1 = rintf(p1), x2 = rintf(p2), y2 = rintf(p3);
    float bwf = fmaxf(x2 - x1 + 1.f, 1.f) * 0.5f;
    float bhf = fmaxf(y2 - y1 + 1.f, 1.f) * 0.5f;
    for (int ph = 0; ph < 2; ph++)
      for (int pw = 0; pw < 2; pw++) {
        int hsv = (int)fminf(fmaxf(floorf((float)ph * bhf) + y1, 0.f), 1080.f);
        int hev = (int)fminf(fmaxf(ceilf((float)(ph + 1) * bhf) + y1, 0.f), 1080.f);
        int wsv = (int)fminf(fmaxf(floorf((float)pw * bwf) + x1, 0.f), 1080.f);
        int wev = (int)fminf(fmaxf(ceilf((float)(pw + 1) * bwf) + x1, 0.f), 1080.f);
        int idx = k * 4 + ph * 2 + pw;
        rects[idx * 4 + 0] = hsv;
        rects[idx * 4 + 1] = hev;
        rects[idx * 4 + 2] = wsv;
        rects[idx * 4 + 3] = wev;
      }
  }
  if (tid >= 32 && tid < 52) pooled_m[tid - 32] = 0x007FFFFFu;  // mapped(-inf)
}

// ============ K5: RoI max pool (atomicMax on order-preserving uint map) ============
__global__ __launch_bounds__(256) void k5_roipool(
    const float* __restrict__ red, const int* __restrict__ rects,
    unsigned* __restrict__ pooled_m) {
  const int cell = blockIdx.x;
  const int hs = rects[cell * 4 + 0], he = rects[cell * 4 + 1];
  const int wss = rects[cell * 4 + 2], wee = rects[cell * 4 + 3];
  const int nr = he - hs;
  if (nr <= 0 || wee <= wss) return;
  const int slice = blockIdx.y, nslice = gridDim.y;
  const int r0 = hs + (int)((long)nr * slice / nslice);
  const int r1 = hs + (int)((long)nr * (slice + 1) / nslice);
  float m = -INFINITY;
  for (int r = r0; r < r1; r++)
    for (int c = wss + (int)threadIdx.x; c < wee; c += 256)
      m = fmaxf(m, red[(size_t)r * FMD + c]);
  __shared__ float part[256];
  part[threadIdx.x] = m;
  __syncthreads();
  for (int s = 128; s > 0; s >>= 1) {
    if ((int)threadIdx.x < s) part[threadIdx.x] = fmaxf(part[threadIdx.x], part[threadIdx.x + s]);
    __syncthreads();
  }
  if (threadIdx.x == 0 && part[0] > -INFINITY) {
    unsigned u = __float_as_uint(part[0]);
    u = (u & 0x80000000u) ? ~u : (u | 0x80000000u);
    atomicMax(&pooled_m[cell], u);
  }
}

// ============ K6: fc / box / cls heads -> d_out (30 floats) ============
__global__ void k6_heads(
    const unsigned* __restrict__ pooled_m, const float* __restrict__ props,
    const float* __restrict__ fcw, const float* __restrict__ fcb,
    const float* __restrict__ bxw, const float* __restrict__ bxb,
    const float* __restrict__ clw, const float* __restrict__ clb,
    float* __restrict__ out) {
  if (threadIdx.x != 0 || blockIdx.x != 0) return;
  float pooled[5][4];
  for (int i = 0; i < 20; i++) {
    unsigned u = pooled_m[i];
    float f = (u & 0x80000000u) ? __uint_as_float(u ^ 0x80000000u) : __uint_as_float(~u);
    if (!isfinite(f)) f = 0.f;
    pooled[i / 4][i % 4] = f;
  }
  for (int k = 0; k < 5; k++) {
    float fc[12];
    for (int m = 0; m < 12; m++) {
      float v = fcb[m];
      for (int n = 0; n < 4; n++) v += pooled[k][n] * fcw[m * 4 + n];
      fc[m] = v;
    }
    float bo[4];
    for (int c = 0; c < 4; c++) {
      float v = bxb[c];
      for (int m = 0; m < 12; m++) v += fc[m] * bxw[c * 12 + m];
      bo[c] = v;
    }
    float p0 = props[k * 4], p1 = props[k * 4 + 1], p2 = props[k * 4 + 2], p3 = props[k * 4 + 3];
    out[k * 4 + 0] = fminf(fmaxf(p0 + bo[0] - bo[2] * 0.5f, 0.f), 3.f);
    out[k * 4 + 1] = fminf(fmaxf(p1 - bo[3] * 0.5f, 0.f), 1.f);
    out[k * 4 + 2] = fminf(fmaxf(p2 + bo[0] + bo[2] * 0.5f, 0.f), 3.f);
    out[k * 4 + 3] = fminf(fmaxf(p3 + bo[3] * 0.5f, 0.f), 1.f);
    float l0 = clb[0], l1 = clb[1];
    for (int m = 0; m < 12; m++) {
      l0 += fc[m] * clw[m];
      l1 += fc[m] * clw[12 + m];
    }
    float mx = fmaxf(l0, l1);
    float e0 = expf(l0 - mx), e1 = expf(l1 - mx);
    out[20 + k * 2 + 0] = e0 / (e0 + e1);
    out[20 + k * 2 + 1] = e1 / (e0 + e1);
  }
}

extern "C" void kernel_launch(void* const* d_in, const int* in_sizes, int n_in,
                              void* d_out, int out_size, void* d_ws, size_t ws_size,
                              hipStream_t stream) {
  const float* x   = (const float*)d_in[0];
  const float* w1  = (const float*)d_in[1];
  const float* b1  = (const float*)d_in[2];
  const float* w2  = (const float*)d_in[3];
  const float* b2  = (const float*)d_in[4];
  const float* w3  = (const float*)d_in[5];
  const float* b3  = (const float*)d_in[6];
  const float* w4  = (const float*)d_in[7];
  const float* b4  = (const float*)d_in[8];
  const float* rw  = (const float*)d_in[9];
  const float* rb  = (const float*)d_in[10];
  const float* bbw = (const float*)d_in[11];
  const float* bbb = (const float*)d_in[12];
  const float* clw = (const float*)d_in[13];
  const float* clb = (const float*)d_in[14];
  const float* fcw = (const float*)d_in[15];
  const float* fcb = (const float*)d_in[16];
  const float* bxw = (const float*)d_in[17];
  const float* bxb = (const float*)d_in[18];
  const float* c2w = (const float*)d_in[19];
  const float* c2b = (const float*)d_in[20];

  float* ws = (float*)d_ws;
  float* h2 = ws + H2_OFF;
  float* red = ws + RED_OFF;
  float* y = ws + Y_OFF;
  float* props = ws + PROPS_OFF;
  int* rects = (int*)(ws + RECTS_OFF);
  unsigned* pooled_m = (unsigned*)(ws + POOL_OFF);

  k1_colstream<<<dim3(9, 270), 256, 0, stream>>>(x, w1, b1, w2, b2, h2);
  k2_colstream<<<dim3(5, 270), 256, 0, stream>>>(h2, w3, b3, w4, b4, red);
  k3_rpnconv<<<441, 256, 0, stream>>>(red, rw, rb, y);
  k4_select<<<1, 512, 0, stream>>>(y, bbw, bbb, clw, clb, props, rects, pooled_m);
  k5_roipool<<<dim3(20, 16), 256, 0, stream>>>(red, rects, pooled_m);
  k6_heads<<<1, 64, 0, stream>>>(pooled_m, props, fcw, fcb, bxw, bxb, c2w, c2b,
                                 (float*)d_out);
}

// Round 6
// 286.255 us; speedup vs baseline: 1.5058x; 1.5058x over previous
//
#include <hip/hip_runtime.h>
#include <math.h>

#define IMG 4320
#define H2D 2160
#define FMD 1080
#define FF 21

typedef unsigned short u16;

__device__ __forceinline__ float bf2f(u16 h) {
  return __uint_as_float(((unsigned)h) << 16);
}
__device__ __forceinline__ u16 f2bf(float f) {  // RTNE
  unsigned u = __float_as_uint(f);
  unsigned r = 0x7FFFu + ((u >> 16) & 1u);
  return (u16)((u + r) >> 16);
}

// ============================================================================
// SPLIT BACKBONE: four simple kernels, global->reg->FMA->store, no LDS.
// ============================================================================

// ---- conv1: x[3,4320,4320] -> c1 bf16 [3,4320,4320]. thread: 2 rows x 4 cols
__global__ __launch_bounds__(256) void k_conv1(
    const float* __restrict__ x, const float* __restrict__ w1,
    const float* __restrict__ b1, u16* __restrict__ c1) {
  const int g = blockIdx.x * 256 + threadIdx.x;
  if (g >= 1080 * 2160) return;
  const int gx = g % 1080, gy = g / 1080;
  const int c0 = gx * 4, r0 = gy * 2;
  const bool okL = gx > 0, okR = gx < 1079;
  float acc[3][2][4];
  #pragma unroll
  for (int oc = 0; oc < 3; ++oc) {
    const float bb = b1[oc];
    #pragma unroll
    for (int r = 0; r < 2; ++r)
      #pragma unroll
      for (int j = 0; j < 4; ++j) acc[oc][r][j] = bb;
  }
  #pragma unroll
  for (int rr = 0; rr < 4; ++rr) {
    const int row = r0 - 1 + rr;
    const bool rok = (unsigned)row < (unsigned)IMG;
    const size_t rbase = (size_t)(rok ? row : 0) * IMG + c0;
    float s[3][6];
    #pragma unroll
    for (int ic = 0; ic < 3; ++ic) {
      const float* bp = x + (size_t)ic * IMG * IMG + rbase;
      float4 m = make_float4(0.f, 0.f, 0.f, 0.f);
      if (rok) m = *(const float4*)bp;
      s[ic][1] = m.x; s[ic][2] = m.y; s[ic][3] = m.z; s[ic][4] = m.w;
      const float* pl = bp + (okL ? -1 : 0);
      const float* pr = bp + (okR ? 4 : 0);
      float vl = 0.f, vr = 0.f;
      if (rok && okL) vl = *pl;
      if (rok && okR) vr = *pr;
      s[ic][0] = vl; s[ic][5] = vr;
    }
    #pragma unroll
    for (int half = 0; half < 2; ++half) {
      if ((half == 0 && rr < 3) || (half == 1 && rr > 0)) {
        const int dy = (half == 0) ? rr : rr - 1;
        #pragma unroll
        for (int oc = 0; oc < 3; ++oc)
          #pragma unroll
          for (int ic = 0; ic < 3; ++ic)
            #pragma unroll
            for (int dx = 0; dx < 3; ++dx) {
              const float w = w1[oc * 27 + ic * 9 + dy * 3 + dx];
              #pragma unroll
              for (int j = 0; j < 4; ++j) acc[oc][half][j] += s[ic][j + dx] * w;
            }
      }
    }
  }
  #pragma unroll
  for (int oc = 0; oc < 3; ++oc)
    #pragma unroll
    for (int r = 0; r < 2; ++r) {
      ushort4 h;
      h.x = f2bf(acc[oc][r][0]); h.y = f2bf(acc[oc][r][1]);
      h.z = f2bf(acc[oc][r][2]); h.w = f2bf(acc[oc][r][3]);
      *(ushort4*)(c1 + (size_t)oc * IMG * IMG + (size_t)(r0 + r) * IMG + c0) = h;
    }
}

// ---- conv2 + 2x2 maxpool: c1 bf16 -> h2 [2,2160,2160]. thread: 2 pooled px
__global__ __launch_bounds__(256) void k_conv2pool(
    const u16* __restrict__ c1, const float* __restrict__ w2,
    const float* __restrict__ b2, float* __restrict__ h2) {
  const int g = blockIdx.x * 256 + threadIdx.x;
  if (g >= 1080 * 2160) return;
  const int gx = g % 1080, py = g / 1080;
  const int c0 = gx * 4, r0 = py * 2;
  const bool okL = gx > 0, okR = gx < 1079;
  float acc[2][2][4];
  #pragma unroll
  for (int oc = 0; oc < 2; ++oc) {
    const float bb = b2[oc];
    #pragma unroll
    for (int r = 0; r < 2; ++r)
      #pragma unroll
      for (int j = 0; j < 4; ++j) acc[oc][r][j] = bb;
  }
  #pragma unroll
  for (int rr = 0; rr < 4; ++rr) {
    const int row = r0 - 1 + rr;
    const bool rok = (unsigned)row < (unsigned)IMG;
    const size_t rbase = (size_t)(rok ? row : 0) * IMG + c0;
    float s[3][6];
    #pragma unroll
    for (int ic = 0; ic < 3; ++ic) {
      const u16* bp = c1 + (size_t)ic * IMG * IMG + rbase;
      ushort4 m = make_ushort4(0, 0, 0, 0);
      if (rok) m = *(const ushort4*)bp;
      s[ic][1] = bf2f(m.x); s[ic][2] = bf2f(m.y);
      s[ic][3] = bf2f(m.z); s[ic][4] = bf2f(m.w);
      const u16* pl = bp + (okL ? -1 : 0);
      const u16* pr = bp + (okR ? 4 : 0);
      u16 vl = 0, vr = 0;
      if (rok && okL) vl = *pl;
      if (rok && okR) vr = *pr;
      s[ic][0] = bf2f(vl); s[ic][5] = bf2f(vr);
    }
    #pragma unroll
    for (int half = 0; half < 2; ++half) {
      if ((half == 0 && rr < 3) || (half == 1 && rr > 0)) {
        const int dy = (half == 0) ? rr : rr - 1;
        #pragma unroll
        for (int oc = 0; oc < 2; ++oc)
          #pragma unroll
          for (int ic = 0; ic < 3; ++ic)
            #pragma unroll
            for (int dx = 0; dx < 3; ++dx) {
              const float w = w2[oc * 27 + ic * 9 + dy * 3 + dx];
              #pragma unroll
              for (int j = 0; j < 4; ++j) acc[oc][half][j] += s[ic][j + dx] * w;
            }
      }
    }
  }
  #pragma unroll
  for (int oc = 0; oc < 2; ++oc) {
    float2 o;
    o.x = fmaxf(fmaxf(acc[oc][0][0], acc[oc][0][1]),
                fmaxf(acc[oc][1][0], acc[oc][1][1]));
    o.y = fmaxf(fmaxf(acc[oc][0][2], acc[oc][0][3]),
                fmaxf(acc[oc][1][2], acc[oc][1][3]));
    *(float2*)(h2 + (size_t)oc * H2D * H2D + (size_t)py * H2D + 2 * gx) = o;
  }
}

// ---- conv3: h2 [2,2160,2160] -> c3 [2,2160,2160]. thread: 2 rows x 4 cols
__global__ __launch_bounds__(256) void k_conv3(
    const float* __restrict__ h2, const float* __restrict__ w3,
    const float* __restrict__ b3, float* __restrict__ c3) {
  const int g = blockIdx.x * 256 + threadIdx.x;
  if (g >= 540 * 1080) return;
  const int gx = g % 540, gy = g / 540;
  const int c0 = gx * 4, r0 = gy * 2;
  const bool okL = gx > 0, okR = gx < 539;
  float acc[2][2][4];
  #pragma unroll
  for (int oc = 0; oc < 2; ++oc) {
    const float bb = b3[oc];
    #pragma unroll
    for (int r = 0; r < 2; ++r)
      #pragma unroll
      for (int j = 0; j < 4; ++j) acc[oc][r][j] = bb;
  }
  #pragma unroll
  for (int rr = 0; rr < 4; ++rr) {
    const int row = r0 - 1 + rr;
    const bool rok = (unsigned)row < (unsigned)H2D;
    const size_t rbase = (size_t)(rok ? row : 0) * H2D + c0;
    float s[2][6];
    #pragma unroll
    for (int ic = 0; ic < 2; ++ic) {
      const float* bp = h2 + (size_t)ic * H2D * H2D + rbase;
      float4 m = make_float4(0.f, 0.f, 0.f, 0.f);
      if (rok) m = *(const float4*)bp;
      s[ic][1] = m.x; s[ic][2] = m.y; s[ic][3] = m.z; s[ic][4] = m.w;
      const float* pl = bp + (okL ? -1 : 0);
      const float* pr = bp + (okR ? 4 : 0);
      float vl = 0.f, vr = 0.f;
      if (rok && okL) vl = *pl;
      if (rok && okR) vr = *pr;
      s[ic][0] = vl; s[ic][5] = vr;
    }
    #pragma unroll
    for (int half = 0; half < 2; ++half) {
      if ((half == 0 && rr < 3) || (half == 1 && rr > 0)) {
        const int dy = (half == 0) ? rr : rr - 1;
        #pragma unroll
        for (int oc = 0; oc < 2; ++oc)
          #pragma unroll
          for (int ic = 0; ic < 2; ++ic)
            #pragma unroll
            for (int dx = 0; dx < 3; ++dx) {
              const float w = w3[oc * 18 + ic * 9 + dy * 3 + dx];
              #pragma unroll
              for (int j = 0; j < 4; ++j) acc[oc][half][j] += s[ic][j + dx] * w;
            }
      }
    }
  }
  #pragma unroll
  for (int oc = 0; oc < 2; ++oc)
    #pragma unroll
    for (int r = 0; r < 2; ++r) {
      float4 o;
      o.x = acc[oc][r][0]; o.y = acc[oc][r][1];
      o.z = acc[oc][r][2]; o.w = acc[oc][r][3];
      *(float4*)(c3 + (size_t)oc * H2D * H2D + (size_t)(r0 + r) * H2D + c0) = o;
    }
}

// ---- conv4 + 2x2 maxpool: c3 -> red [1080,1080]. thread: 2 pooled px
__global__ __launch_bounds__(256) void k_conv4pool(
    const float* __restrict__ c3, const float* __restrict__ w4,
    const float* __restrict__ b4, float* __restrict__ red) {
  const int g = blockIdx.x * 256 + threadIdx.x;
  if (g >= 540 * 1080) return;
  const int gx = g % 540, py = g / 540;
  const int c0 = gx * 4, r0 = py * 2;
  const bool okL = gx > 0, okR = gx < 539;
  const float bb = b4[0];
  float acc[2][4];
  #pragma unroll
  for (int r = 0; r < 2; ++r)
    #pragma unroll
    for (int j = 0; j < 4; ++j) acc[r][j] = bb;
  #pragma unroll
  for (int rr = 0; rr < 4; ++rr) {
    const int row = r0 - 1 + rr;
    const bool rok = (unsigned)row < (unsigned)H2D;
    const size_t rbase = (size_t)(rok ? row : 0) * H2D + c0;
    float s[2][6];
    #pragma unroll
    for (int ic = 0; ic < 2; ++ic) {
      const float* bp = c3 + (size_t)ic * H2D * H2D + rbase;
      float4 m = make_float4(0.f, 0.f, 0.f, 0.f);
      if (rok) m = *(const float4*)bp;
      s[ic][1] = m.x; s[ic][2] = m.y; s[ic][3] = m.z; s[ic][4] = m.w;
      const float* pl = bp + (okL ? -1 : 0);
      const float* pr = bp + (okR ? 4 : 0);
      float vl = 0.f, vr = 0.f;
      if (rok && okL) vl = *pl;
      if (rok && okR) vr = *pr;
      s[ic][0] = vl; s[ic][5] = vr;
    }
    #pragma unroll
    for (int half = 0; half < 2; ++half) {
      if ((half == 0 && rr < 3) || (half == 1 && rr > 0)) {
        const int dy = (half == 0) ? rr : rr - 1;
        #pragma unroll
        for (int ic = 0; ic < 2; ++ic)
          #pragma unroll
          for (int dx = 0; dx < 3; ++dx) {
            const float w = w4[ic * 9 + dy * 3 + dx];
            #pragma unroll
            for (int j = 0; j < 4; ++j) acc[half][j] += s[ic][j + dx] * w;
          }
      }
    }
  }
  float2 o;
  o.x = fmaxf(fmaxf(acc[0][0], acc[0][1]), fmaxf(acc[1][0], acc[1][1]));
  o.y = fmaxf(fmaxf(acc[0][2], acc[0][3]), fmaxf(acc[1][2], acc[1][3]));
  *(float2*)(red + (size_t)py * FMD + 2 * gx) = o;
}

// ============================================================================
// FALLBACK (ws too small): round-2 fused LDS kernels (proven, 246 us)
// ============================================================================
__global__ __launch_bounds__(256) void k1_backbone1(
    const float* __restrict__ x,
    const float* __restrict__ w1, const float* __restrict__ b1,
    const float* __restrict__ w2, const float* __restrict__ b2,
    float* __restrict__ h2) {
  __shared__ float xs[3][34][36];
  __shared__ float c1s[3][32][36];
  const int tid = threadIdx.x;
  const int bx = blockIdx.x, by = blockIdx.y;
  const int gy0 = by * 30 - 2, gx0 = bx * 30 - 2;
  float W1[81], B1[3];
  #pragma unroll
  for (int i = 0; i < 81; ++i) W1[i] = w1[i];
  #pragma unroll
  for (int i = 0; i < 3; ++i) B1[i] = b1[i];
  for (int l = tid; l < 3 * 34 * 34; l += 256) {
    int c = l / 1156, rem = l % 1156, r = rem / 34, cc = rem % 34;
    int gy = gy0 + r, gx = gx0 + cc;
    float v = 0.f;
    if ((unsigned)gy < IMG && (unsigned)gx < IMG)
      v = x[(size_t)c * IMG * IMG + (size_t)gy * IMG + gx];
    xs[c][r][cc] = v;
  }
  __syncthreads();
  {
    const int r = tid >> 3;
    const int c4 = (tid & 7) << 2;
    float acc[3][4];
    #pragma unroll
    for (int oc = 0; oc < 3; ++oc)
      #pragma unroll
      for (int j = 0; j < 4; ++j) acc[oc][j] = B1[oc];
    #pragma unroll
    for (int ic = 0; ic < 3; ++ic) {
      float xr[3][8];
      #pragma unroll
      for (int dy = 0; dy < 3; ++dy) {
        const float4 q0 = *(const float4*)&xs[ic][r + dy][c4];
        const float4 q1 = *(const float4*)&xs[ic][r + dy][c4 + 4];
        xr[dy][0] = q0.x; xr[dy][1] = q0.y; xr[dy][2] = q0.z; xr[dy][3] = q0.w;
        xr[dy][4] = q1.x; xr[dy][5] = q1.y; xr[dy][6] = q1.z; xr[dy][7] = q1.w;
      }
      #pragma unroll
      for (int oc = 0; oc < 3; ++oc)
        #pragma unroll
        for (int dy = 0; dy < 3; ++dy)
          #pragma unroll
          for (int dx = 0; dx < 3; ++dx) {
            const float w = W1[oc * 27 + ic * 9 + dy * 3 + dx];
            #pragma unroll
            for (int j = 0; j < 4; ++j) acc[oc][j] += xr[dy][j + dx] * w;
          }
    }
    const int gy = by * 30 - 1 + r;
    const bool rOK = (unsigned)gy < IMG;
    const int gxb = bx * 30 - 1 + c4;
    #pragma unroll
    for (int oc = 0; oc < 3; ++oc) {
      float4 o;
      o.x = (rOK && (unsigned)(gxb + 0) < IMG) ? acc[oc][0] : 0.f;
      o.y = (rOK && (unsigned)(gxb + 1) < IMG) ? acc[oc][1] : 0.f;
      o.z = (rOK && (unsigned)(gxb + 2) < IMG) ? acc[oc][2] : 0.f;
      o.w = (rOK && (unsigned)(gxb + 3) < IMG) ? acc[oc][3] : 0.f;
      *(float4*)&c1s[oc][r][c4] = o;
    }
  }
  __syncthreads();
  float W2[54], B2[2];
  #pragma unroll
  for (int i = 0; i < 54; ++i) W2[i] = w2[i];
  B2[0] = b2[0]; B2[1] = b2[1];
  const int ty = tid >> 4, tx = tid & 15;
  if (ty < 15 && tx < 15) {
    float cr[3][4][4];
    #pragma unroll
    for (int ic = 0; ic < 3; ++ic)
      #pragma unroll
      for (int rr = 0; rr < 4; ++rr) {
        const float2 p0 = *(const float2*)&c1s[ic][2 * ty + rr][2 * tx];
        const float2 p1 = *(const float2*)&c1s[ic][2 * ty + rr][2 * tx + 2];
        cr[ic][rr][0] = p0.x; cr[ic][rr][1] = p0.y;
        cr[ic][rr][2] = p1.x; cr[ic][rr][3] = p1.y;
      }
    float m0 = -INFINITY, m1 = -INFINITY;
    #pragma unroll
    for (int sy = 0; sy < 2; ++sy)
      #pragma unroll
      for (int sx = 0; sx < 2; ++sx) {
        float a0 = B2[0], a1 = B2[1];
        #pragma unroll
        for (int ic = 0; ic < 3; ++ic)
          #pragma unroll
          for (int dy = 0; dy < 3; ++dy)
            #pragma unroll
            for (int dx = 0; dx < 3; ++dx) {
              const float v = cr[ic][sy + dy][sx + dx];
              a0 += v * W2[ic * 9 + dy * 3 + dx];
              a1 += v * W2[27 + ic * 9 + dy * 3 + dx];
            }
        m0 = fmaxf(m0, a0);
        m1 = fmaxf(m1, a1);
      }
    const size_t o = (size_t)(by * 15 + ty) * H2D + (bx * 15 + tx);
    h2[o] = m0;
    h2[(size_t)H2D * H2D + o] = m1;
  }
}

__global__ __launch_bounds__(256) void k2_backbone2(
    const float* __restrict__ h2,
    const float* __restrict__ w3, const float* __restrict__ b3,
    const float* __restrict__ w4, const float* __restrict__ b4,
    float* __restrict__ red) {
  __shared__ float hs[2][34][36];
  __shared__ float c3s[2][32][36];
  const int tid = threadIdx.x;
  const int bx = blockIdx.x, by = blockIdx.y;
  const int gy0 = by * 30 - 2, gx0 = bx * 30 - 2;
  float W3[36], B3[2];
  #pragma unroll
  for (int i = 0; i < 36; ++i) W3[i] = w3[i];
  B3[0] = b3[0]; B3[1] = b3[1];
  for (int l = tid; l < 2 * 34 * 34; l += 256) {
    int c = l / 1156, rem = l % 1156, r = rem / 34, cc = rem % 34;
    int gy = gy0 + r, gx = gx0 + cc;
    float v = 0.f;
    if ((unsigned)gy < H2D && (unsigned)gx < H2D)
      v = h2[(size_t)c * H2D * H2D + (size_t)gy * H2D + gx];
    hs[c][r][cc] = v;
  }
  __syncthreads();
  {
    const int r = tid >> 3;
    const int c4 = (tid & 7) << 2;
    float acc[2][4];
    #pragma unroll
    for (int oc = 0; oc < 2; ++oc)
      #pragma unroll
      for (int j = 0; j < 4; ++j) acc[oc][j] = B3[oc];
    #pragma unroll
    for (int ic = 0; ic < 2; ++ic) {
      float xr[3][8];
      #pragma unroll
      for (int dy = 0; dy < 3; ++dy) {
        const float4 q0 = *(const float4*)&hs[ic][r + dy][c4];
        const float4 q1 = *(const float4*)&hs[ic][r + dy][c4 + 4];
        xr[dy][0] = q0.x; xr[dy][1] = q0.y; xr[dy][2] = q0.z; xr[dy][3] = q0.w;
        xr[dy][4] = q1.x; xr[dy][5] = q1.y; xr[dy][6] = q1.z; xr[dy][7] = q1.w;
      }
      #pragma unroll
      for (int oc = 0; oc < 2; ++oc)
        #pragma unroll
        for (int dy = 0; dy < 3; ++dy)
          #pragma unroll
          for (int dx = 0; dx < 3; ++dx) {
            const float w = W3[oc * 18 + ic * 9 + dy * 3 + dx];
            #pragma unroll
            for (int j = 0; j < 4; ++j) acc[oc][j] += xr[dy][j + dx] * w;
          }
    }
    const int gy = by * 30 - 1 + r;
    const bool rOK = (unsigned)gy < H2D;
    const int gxb = bx * 30 - 1 + c4;
    #pragma unroll
    for (int oc = 0; oc < 2; ++oc) {
      float4 o;
      o.x = (rOK && (unsigned)(gxb + 0) < H2D) ? acc[oc][0] : 0.f;
      o.y = (rOK && (unsigned)(gxb + 1) < H2D) ? acc[oc][1] : 0.f;
      o.z = (rOK && (unsigned)(gxb + 2) < H2D) ? acc[oc][2] : 0.f;
      o.w = (rOK && (unsigned)(gxb + 3) < H2D) ? acc[oc][3] : 0.f;
      *(float4*)&c3s[oc][r][c4] = o;
    }
  }
  __syncthreads();
  float W4[18], B4;
  #pragma unroll
  for (int i = 0; i < 18; ++i) W4[i] = w4[i];
  B4 = b4[0];
  const int ty = tid >> 4, tx = tid & 15;
  if (ty < 15 && tx < 15) {
    float cr[2][4][4];
    #pragma unroll
    for (int ic = 0; ic < 2; ++ic)
      #pragma unroll
      for (int rr = 0; rr < 4; ++rr) {
        const float2 p0 = *(const float2*)&c3s[ic][2 * ty + rr][2 * tx];
        const float2 p1 = *(const float2*)&c3s[ic][2 * ty + rr][2 * tx + 2];
        cr[ic][rr][0] = p0.x; cr[ic][rr][1] = p0.y;
        cr[ic][rr][2] = p1.x; cr[ic][rr][3] = p1.y;
      }
    float m = -INFINITY;
    #pragma unroll
    for (int sy = 0; sy < 2; ++sy)
      #pragma unroll
      for (int sx = 0; sx < 2; ++sx) {
        float a = B4;
        #pragma unroll
        for (int ic = 0; ic < 2; ++ic)
          #pragma unroll
          for (int dy = 0; dy < 3; ++dy)
            #pragma unroll
            for (int dx = 0; dx < 3; ++dx)
              a += cr[ic][sy + dy][sx + dx] * W4[ic * 9 + dy * 3 + dx];
        m = fmaxf(m, a);
      }
    red[(size_t)(by * 15 + ty) * FMD + (bx * 15 + tx)] = m;
  }
}

// ============ K3: rpn_conv (50x50, stride 50)  (reduced -> y [2,21,21]) ============
__global__ __launch_bounds__(256) void k3_rpnconv(
    const float* __restrict__ red,
    const float* __restrict__ w, const float* __restrict__ b,
    float* __restrict__ y) {
  __shared__ float part[256];
  const int cell = blockIdx.x;
  const int i = cell / FF, j = cell % FF;
  const int tid = threadIdx.x;
  float a0 = 0.f, a1 = 0.f;
  for (int t = tid; t < 2500; t += 256) {
    int ay = t / 50, ax = t % 50;
    float v = red[(size_t)(50 * i + ay) * FMD + 50 * j + ax];
    a0 += v * w[t];
    a1 += v * w[2500 + t];
  }
  part[tid] = a0;
  __syncthreads();
  for (int s = 128; s > 0; s >>= 1) {
    if (tid < s) part[tid] += part[tid + s];
    __syncthreads();
  }
  if (tid == 0) y[cell] = part[0] + b[0];
  __syncthreads();
  part[tid] = a1;
  __syncthreads();
  for (int s = 128; s > 0; s >>= 1) {
    if (tid < s) part[tid] += part[tid + s];
    __syncthreads();
  }
  if (tid == 0) y[441 + cell] = part[0] + b[1];
}

// ============ K4: rpn heads + faithful masked-select + proposals/rects ============
__global__ __launch_bounds__(512) void k4_select(
    const float* __restrict__ y,
    const float* __restrict__ bbw, const float* __restrict__ bbb,
    const float* __restrict__ clw, const float* __restrict__ clb,
    float* __restrict__ props_out, int* __restrict__ rects,
    unsigned* __restrict__ pooled_m) {
  __shared__ float ys[2][23][23];
  __shared__ unsigned char flag[6][441];
  __shared__ short pos[6][20];
  __shared__ int cnt[6];
  __shared__ int selT[20];
  __shared__ float offv[20], anchv[20];
  const int tid = threadIdx.x;
  for (int l = tid; l < 2 * 23 * 23; l += 512) ((float*)ys)[l] = 0.f;
  __syncthreads();
  for (int l = tid; l < 2 * 441; l += 512) {
    int c = l / 441, p = l % 441;
    ys[c][p / 21 + 1][p % 21 + 1] = y[l];
  }
  __syncthreads();
  for (int l = tid; l < 6 * 441; l += 512) {
    int a = l / 441, p = l % 441, i = p / 21, j = p % 21;
    float v = clb[a];
    #pragma unroll
    for (int c2 = 0; c2 < 2; c2++)
      #pragma unroll
      for (int dy = 0; dy < 3; dy++)
        #pragma unroll
        for (int dx = 0; dx < 3; dx++)
          v += ys[c2][i + dy][j + dx] * clw[a * 18 + c2 * 9 + dy * 3 + dx];
    flag[a][p] = (tanhf(v) > 0.95f) ? 1 : 0;
  }
  __syncthreads();
  if (tid < 6) {
    int c = 0;
    for (int p = 0; p < 441; p++)
      if (flag[tid][p]) {
        if (c < 20) pos[tid][c] = (short)p;
        c++;
      }
    cnt[tid] = c;
  }
  __syncthreads();
  if (tid == 0) {
    int s = 0;
    for (int g = 0; g < 24 && s < 20; g++) {
      int a = g >> 2;
      int take = cnt[a] < 20 - s ? cnt[a] : 20 - s;
      for (int r = 0; r < take; r++) selT[s++] = g * 441 + (int)pos[a][r];
    }
    if (s < 20) {
      for (int t = 0; t < 10584 && s < 20; t++) {
        int a = t / 1764, p = t % 441;
        if (!flag[a][p]) selT[s++] = t;
      }
    }
  }
  __syncthreads();
  if (tid < 20) {
    int t = selT[tid];
    int ch = t / 441, p = t % 441, i = p / 21, j = p % 21;
    int a = ch >> 2, c = ch & 3;
    float v = bbb[ch];
    #pragma unroll
    for (int c2 = 0; c2 < 2; c2++)
      #pragma unroll
      for (int dy = 0; dy < 3; dy++)
        #pragma unroll
        for (int dx = 0; dx < 3; dx++)
          v += ys[c2][i + dy][j + dx] * bbw[ch * 18 + c2 * 9 + dy * 3 + dx];
    offv[tid] = v;
    float sz = (a < 3) ? 1.f : 2.f;
    int am = a % 3;
    float ar = (am == 0) ? 0.5f : (am == 1 ? 1.f : 2.f);
    float base;
    if (c == 0) base = 0.f;
    else if (c == 1) base = sz * -(ar - 1.f) * 0.5f;
    else if (c == 2) base = sz;
    else base = sz * (1.f + (ar - 1.f) * 0.5f);
    anchv[tid] = base + ((c & 1) ? (float)j : (float)i);
  }
  __syncthreads();
  if (tid < 5) {
    int k = tid;
    float o0 = offv[4 * k], o1 = offv[4 * k + 1], o2 = offv[4 * k + 2], o3 = offv[4 * k + 3];
    float a0 = anchv[4 * k], a2 = anchv[4 * k + 2], a3 = anchv[4 * k + 3];
    float p0 = fminf(fmaxf(o0 + a0 - a2 * 0.5f, 0.f), 21.f) * 50.f;
    float p1 = fminf(fmaxf(o1 - a3 * 0.5f, 0.f), 21.f) * 50.f;
    float p2 = fminf(fmaxf(o2 + a0 + a2 * 0.5f, 0.f), 21.f) * 50.f;
    float p3 = fminf(fmaxf(o3 + a3 * 0.5f, 0.f), 21.f) * 50.f;
    props_out[k * 4 + 0] = p0;
    props_out[k * 4 + 1] = p1;
    props_out[k * 4 + 2] = p2;
    props_out[k * 4 + 3] = p3;
    float x1 = rintf(p0), y1 = rintf(p1), x2 = rintf(p2), y2 = rintf(p3);
    float bwf = fmaxf(x2 - x1 + 1.f, 1.f) * 0.5f;
    float bhf = fmaxf(y2 - y1 + 1.f, 1.f) * 0.5f;
    for (int ph = 0; ph < 2; ph++)
      for (int pw = 0; pw < 2; pw++) {
        int hsv = (int)fminf(fmaxf(floorf((float)ph * bhf) + y1, 0.f), 1080.f);
        int hev = (int)fminf(fmaxf(ceilf((float)(ph + 1) * bhf) + y1, 0.f), 1080.f);
        int wsv = (int)fminf(fmaxf(floorf((float)pw * bwf) + x1, 0.f), 1080.f);
        int wev = (int)fminf(fmaxf(ceilf((float)(pw + 1) * bwf) + x1, 0.f), 1080.f);
        int idx = k * 4 + ph * 2 + pw;
        rects[idx * 4 + 0] = hsv;
        rects[idx * 4 + 1] = hev;
        rects[idx * 4 + 2] = wsv;
        rects[idx * 4 + 3] = wev;
      }
  }
  if (tid >= 32 && tid < 52) pooled_m[tid - 32] = 0x007FFFFFu;  // mapped(-inf)
}

// ============ K5: RoI max pool (atomicMax on order-preserving uint map) ============
__global__ __launch_bounds__(256) void k5_roipool(
    const float* __restrict__ red, const int* __restrict__ rects,
    unsigned* __restrict__ pooled_m) {
  const int cell = blockIdx.x;
  const int hs = rects[cell * 4 + 0], he = rects[cell * 4 + 1];
  const int wss = rects[cell * 4 + 2], wee = rects[cell * 4 + 3];
  const int nr = he - hs;
  if (nr <= 0 || wee <= wss) return;
  const int slice = blockIdx.y, nslice = gridDim.y;
  const int r0 = hs + (int)((long)nr * slice / nslice);
  const int r1 = hs + (int)((long)nr * (slice + 1) / nslice);
  float m = -INFINITY;
  for (int r = r0; r < r1; r++)
    for (int c = wss + (int)threadIdx.x; c < wee; c += 256)
      m = fmaxf(m, red[(size_t)r * FMD + c]);
  __shared__ float part[256];
  part[threadIdx.x] = m;
  __syncthreads();
  for (int s = 128; s > 0; s >>= 1) {
    if ((int)threadIdx.x < s) part[threadIdx.x] = fmaxf(part[threadIdx.x], part[threadIdx.x + s]);
    __syncthreads();
  }
  if (threadIdx.x == 0 && part[0] > -INFINITY) {
    unsigned u = __float_as_uint(part[0]);
    u = (u & 0x80000000u) ? ~u : (u | 0x80000000u);
    atomicMax(&pooled_m[cell], u);
  }
}

// ============ K6: fc / box / cls heads -> d_out (30 floats) ============
__global__ void k6_heads(
    const unsigned* __restrict__ pooled_m, const float* __restrict__ props,
    const float* __restrict__ fcw, const float* __restrict__ fcb,
    const float* __restrict__ bxw, const float* __restrict__ bxb,
    const float* __restrict__ clw, const float* __restrict__ clb,
    float* __restrict__ out) {
  if (threadIdx.x != 0 || blockIdx.x != 0) return;
  float pooled[5][4];
  for (int i = 0; i < 20; i++) {
    unsigned u = pooled_m[i];
    float f = (u & 0x80000000u) ? __uint_as_float(u ^ 0x80000000u) : __uint_as_float(~u);
    if (!isfinite(f)) f = 0.f;
    pooled[i / 4][i % 4] = f;
  }
  for (int k = 0; k < 5; k++) {
    float fc[12];
    for (int m = 0; m < 12; m++) {
      float v = fcb[m];
      for (int n = 0; n < 4; n++) v += pooled[k][n] * fcw[m * 4 + n];
      fc[m] = v;
    }
    float bo[4];
    for (int c = 0; c < 4; c++) {
      float v = bxb[c];
      for (int m = 0; m < 12; m++) v += fc[m] * bxw[c * 12 + m];
      bo[c] = v;
    }
    float p0 = props[k * 4], p1 = props[k * 4 + 1], p2 = props[k * 4 + 2], p3 = props[k * 4 + 3];
    out[k * 4 + 0] = fminf(fmaxf(p0 + bo[0] - bo[2] * 0.5f, 0.f), 3.f);
    out[k * 4 + 1] = fminf(fmaxf(p1 - bo[3] * 0.5f, 0.f), 1.f);
    out[k * 4 + 2] = fminf(fmaxf(p2 + bo[0] + bo[2] * 0.5f, 0.f), 3.f);
    out[k * 4 + 3] = fminf(fmaxf(p3 + bo[3] * 0.5f, 0.f), 1.f);
    float l0 = clb[0], l1 = clb[1];
    for (int m = 0; m < 12; m++) {
      l0 += fc[m] * clw[m];
      l1 += fc[m] * clw[12 + m];
    }
    float mx = fmaxf(l0, l1);
    float e0 = expf(l0 - mx), e1 = expf(l1 - mx);
    out[20 + k * 2 + 0] = e0 / (e0 + e1);
    out[20 + k * 2 + 1] = e1 / (e0 + e1);
  }
}

extern "C" void kernel_launch(void* const* d_in, const int* in_sizes, int n_in,
                              void* d_out, int out_size, void* d_ws, size_t ws_size,
                              hipStream_t stream) {
  const float* x   = (const float*)d_in[0];
  const float* w1  = (const float*)d_in[1];
  const float* b1  = (const float*)d_in[2];
  const float* w2  = (const float*)d_in[3];
  const float* b2  = (const float*)d_in[4];
  const float* w3  = (const float*)d_in[5];
  const float* b3  = (const float*)d_in[6];
  const float* w4  = (const float*)d_in[7];
  const float* b4  = (const float*)d_in[8];
  const float* rw  = (const float*)d_in[9];
  const float* rb  = (const float*)d_in[10];
  const float* bbw = (const float*)d_in[11];
  const float* bbb = (const float*)d_in[12];
  const float* clw = (const float*)d_in[13];
  const float* clb = (const float*)d_in[14];
  const float* fcw = (const float*)d_in[15];
  const float* fcb = (const float*)d_in[16];
  const float* bxw = (const float*)d_in[17];
  const float* bxb = (const float*)d_in[18];
  const float* c2w = (const float*)d_in[19];
  const float* c2b = (const float*)d_in[20];

  char* wsb = (char*)d_ws;

  if (ws_size >= 160000000ull) {
    // split path: c1(bf16) 0..111,974,400 | h2 | red | small; c3 aliases c1
    u16*   c1u = (u16*)wsb;
    float* h2  = (float*)(wsb + 111974400);
    float* c3  = (float*)wsb;
    float* red = (float*)(wsb + 149299200);
    float* yv  = (float*)(wsb + 153964800);
    float* props = yv + 882;
    int*   rects = (int*)(props + 20);
    unsigned* pooled_m = (unsigned*)(rects + 80);

    k_conv1   <<<9113, 256, 0, stream>>>(x, w1, b1, c1u);
    k_conv2pool<<<9113, 256, 0, stream>>>(c1u, w2, b2, h2);
    k_conv3   <<<2279, 256, 0, stream>>>(h2, w3, b3, c3);
    k_conv4pool<<<2279, 256, 0, stream>>>(c3, w4, b4, red);
    k3_rpnconv<<<441, 256, 0, stream>>>(red, rw, rb, yv);
    k4_select<<<1, 512, 0, stream>>>(yv, bbw, bbb, clw, clb, props, rects, pooled_m);
    k5_roipool<<<dim3(20, 16), 256, 0, stream>>>(red, rects, pooled_m);
    k6_heads<<<1, 64, 0, stream>>>(pooled_m, props, fcw, fcb, bxw, bxb, c2w, c2b,
                                   (float*)d_out);
  } else {
    // fallback: round-2 fused path (42 MB workspace)
    float* ws = (float*)d_ws;
    float* h2 = ws;
    float* red = ws + 9331200;
    float* yv = ws + 10497600;
    float* props = ws + 10498482;
    int* rects = (int*)(ws + 10498502);
    unsigned* pooled_m = (unsigned*)(ws + 10498582);

    k1_backbone1<<<dim3(144, 144), 256, 0, stream>>>(x, w1, b1, w2, b2, h2);
    k2_backbone2<<<dim3(72, 72), 256, 0, stream>>>(h2, w3, b3, w4, b4, red);
    k3_rpnconv<<<441, 256, 0, stream>>>(red, rw, rb, yv);
    k4_select<<<1, 512, 0, stream>>>(yv, bbw, bbb, clw, clb, props, rects, pooled_m);
    k5_roipool<<<dim3(20, 16), 256, 0, stream>>>(red, rects, pooled_m);
    k6_heads<<<1, 64, 0, stream>>>(pooled_m, props, fcw, fcb, bxw, bxb, c2w, c2b,
                                   (float*)d_out);
  }
}

// Round 7
// 239.351 us; speedup vs baseline: 1.8009x; 1.1960x over previous
//
#include <hip/hip_runtime.h>
#include <math.h>

#define IMG 4320
#define H2D 2160
#define FMD 1080
#define FF 21

typedef unsigned short u16;

__device__ __forceinline__ float bf2f(u16 h) {
  return __uint_as_float(((unsigned)h) << 16);
}
__device__ __forceinline__ u16 f2bf(float f) {  // RTNE
  unsigned u = __float_as_uint(f);
  unsigned r = 0x7FFFu + ((u >> 16) & 1u);
  return (u16)((u + r) >> 16);
}

// ============================================================================
// SPLIT BACKBONE, branch-free batched loads:
//   phase 1 = issue ALL staged loads from clamped (always in-bounds) addresses
//   phase 2 = cndmask-select edge zeros + FMA
// No control flow around loads -> compiler can keep all ~36 loads in flight
// behind one waitcnt instead of ~12 serialized vmcnt(0) groups.
// ============================================================================

// ---- conv1: x[3,4320,4320] -> c1 bf16 [3,4320,4320]. thread: 2 rows x 4 cols
__global__ __launch_bounds__(256, 4) void k_conv1(
    const float* __restrict__ x, const float* __restrict__ w1,
    const float* __restrict__ b1, u16* __restrict__ c1) {
  const int g = blockIdx.x * 256 + threadIdx.x;
  if (g >= 1080 * 2160) return;
  const int gx = g % 1080, gy = g / 1080;
  const int c0 = gx * 4, r0 = gy * 2;
  const bool okL = gx > 0, okR = gx < 1079;

  // ---- phase 1: stage all 36 loads (branch-free) ----
  float4 m[4][3];
  float vl[4][3], vr[4][3];
  bool rokf[4];
  #pragma unroll
  for (int rr = 0; rr < 4; ++rr) {
    const int row = r0 - 1 + rr;
    const bool rok = (unsigned)row < (unsigned)IMG;
    rokf[rr] = rok;
    const size_t rbase = (size_t)(rok ? row : 0) * IMG + c0;
    #pragma unroll
    for (int ic = 0; ic < 3; ++ic) {
      const float* bp = x + (size_t)ic * IMG * IMG + rbase;
      m[rr][ic] = *(const float4*)bp;
      vl[rr][ic] = bp[okL ? -1 : 0];
      vr[rr][ic] = bp[okR ? 4 : 0];
    }
  }

  // ---- phase 2: select + FMA ----
  float acc[3][2][4];
  #pragma unroll
  for (int oc = 0; oc < 3; ++oc) {
    const float bb = b1[oc];
    #pragma unroll
    for (int r = 0; r < 2; ++r)
      #pragma unroll
      for (int j = 0; j < 4; ++j) acc[oc][r][j] = bb;
  }
  #pragma unroll
  for (int rr = 0; rr < 4; ++rr) {
    const bool rok = rokf[rr];
    float s[3][6];
    #pragma unroll
    for (int ic = 0; ic < 3; ++ic) {
      s[ic][0] = (rok && okL) ? vl[rr][ic] : 0.f;
      s[ic][1] = rok ? m[rr][ic].x : 0.f;
      s[ic][2] = rok ? m[rr][ic].y : 0.f;
      s[ic][3] = rok ? m[rr][ic].z : 0.f;
      s[ic][4] = rok ? m[rr][ic].w : 0.f;
      s[ic][5] = (rok && okR) ? vr[rr][ic] : 0.f;
    }
    #pragma unroll
    for (int half = 0; half < 2; ++half) {
      if ((half == 0 && rr < 3) || (half == 1 && rr > 0)) {
        const int dy = (half == 0) ? rr : rr - 1;
        #pragma unroll
        for (int oc = 0; oc < 3; ++oc)
          #pragma unroll
          for (int ic = 0; ic < 3; ++ic)
            #pragma unroll
            for (int dx = 0; dx < 3; ++dx) {
              const float w = w1[oc * 27 + ic * 9 + dy * 3 + dx];
              #pragma unroll
              for (int j = 0; j < 4; ++j) acc[oc][half][j] += s[ic][j + dx] * w;
            }
      }
    }
  }
  #pragma unroll
  for (int oc = 0; oc < 3; ++oc)
    #pragma unroll
    for (int r = 0; r < 2; ++r) {
      ushort4 h;
      h.x = f2bf(acc[oc][r][0]); h.y = f2bf(acc[oc][r][1]);
      h.z = f2bf(acc[oc][r][2]); h.w = f2bf(acc[oc][r][3]);
      *(ushort4*)(c1 + (size_t)oc * IMG * IMG + (size_t)(r0 + r) * IMG + c0) = h;
    }
}

// ---- conv2 + 2x2 maxpool: c1 bf16 -> h2 [2,2160,2160]. thread: 2 pooled px
__global__ __launch_bounds__(256, 4) void k_conv2pool(
    const u16* __restrict__ c1, const float* __restrict__ w2,
    const float* __restrict__ b2, float* __restrict__ h2) {
  const int g = blockIdx.x * 256 + threadIdx.x;
  if (g >= 1080 * 2160) return;
  const int gx = g % 1080, py = g / 1080;
  const int c0 = gx * 4, r0 = py * 2;
  const bool okL = gx > 0, okR = gx < 1079;

  ushort4 m[4][3];
  u16 vl[4][3], vr[4][3];
  bool rokf[4];
  #pragma unroll
  for (int rr = 0; rr < 4; ++rr) {
    const int row = r0 - 1 + rr;
    const bool rok = (unsigned)row < (unsigned)IMG;
    rokf[rr] = rok;
    const size_t rbase = (size_t)(rok ? row : 0) * IMG + c0;
    #pragma unroll
    for (int ic = 0; ic < 3; ++ic) {
      const u16* bp = c1 + (size_t)ic * IMG * IMG + rbase;
      m[rr][ic] = *(const ushort4*)bp;
      vl[rr][ic] = bp[okL ? -1 : 0];
      vr[rr][ic] = bp[okR ? 4 : 0];
    }
  }

  float acc[2][2][4];
  #pragma unroll
  for (int oc = 0; oc < 2; ++oc) {
    const float bb = b2[oc];
    #pragma unroll
    for (int r = 0; r < 2; ++r)
      #pragma unroll
      for (int j = 0; j < 4; ++j) acc[oc][r][j] = bb;
  }
  #pragma unroll
  for (int rr = 0; rr < 4; ++rr) {
    const bool rok = rokf[rr];
    float s[3][6];
    #pragma unroll
    for (int ic = 0; ic < 3; ++ic) {
      s[ic][0] = (rok && okL) ? bf2f(vl[rr][ic]) : 0.f;
      s[ic][1] = rok ? bf2f(m[rr][ic].x) : 0.f;
      s[ic][2] = rok ? bf2f(m[rr][ic].y) : 0.f;
      s[ic][3] = rok ? bf2f(m[rr][ic].z) : 0.f;
      s[ic][4] = rok ? bf2f(m[rr][ic].w) : 0.f;
      s[ic][5] = (rok && okR) ? bf2f(vr[rr][ic]) : 0.f;
    }
    #pragma unroll
    for (int half = 0; half < 2; ++half) {
      if ((half == 0 && rr < 3) || (half == 1 && rr > 0)) {
        const int dy = (half == 0) ? rr : rr - 1;
        #pragma unroll
        for (int oc = 0; oc < 2; ++oc)
          #pragma unroll
          for (int ic = 0; ic < 3; ++ic)
            #pragma unroll
            for (int dx = 0; dx < 3; ++dx) {
              const float w = w2[oc * 27 + ic * 9 + dy * 3 + dx];
              #pragma unroll
              for (int j = 0; j < 4; ++j) acc[oc][half][j] += s[ic][j + dx] * w;
            }
      }
    }
  }
  #pragma unroll
  for (int oc = 0; oc < 2; ++oc) {
    float2 o;
    o.x = fmaxf(fmaxf(acc[oc][0][0], acc[oc][0][1]),
                fmaxf(acc[oc][1][0], acc[oc][1][1]));
    o.y = fmaxf(fmaxf(acc[oc][0][2], acc[oc][0][3]),
                fmaxf(acc[oc][1][2], acc[oc][1][3]));
    *(float2*)(h2 + (size_t)oc * H2D * H2D + (size_t)py * H2D + 2 * gx) = o;
  }
}

// ---- conv3: h2 [2,2160,2160] -> c3 [2,2160,2160]. thread: 2 rows x 4 cols
__global__ __launch_bounds__(256, 4) void k_conv3(
    const float* __restrict__ h2, const float* __restrict__ w3,
    const float* __restrict__ b3, float* __restrict__ c3) {
  const int g = blockIdx.x * 256 + threadIdx.x;
  if (g >= 540 * 1080) return;
  const int gx = g % 540, gy = g / 540;
  const int c0 = gx * 4, r0 = gy * 2;
  const bool okL = gx > 0, okR = gx < 539;

  float4 m[4][2];
  float vl[4][2], vr[4][2];
  bool rokf[4];
  #pragma unroll
  for (int rr = 0; rr < 4; ++rr) {
    const int row = r0 - 1 + rr;
    const bool rok = (unsigned)row < (unsigned)H2D;
    rokf[rr] = rok;
    const size_t rbase = (size_t)(rok ? row : 0) * H2D + c0;
    #pragma unroll
    for (int ic = 0; ic < 2; ++ic) {
      const float* bp = h2 + (size_t)ic * H2D * H2D + rbase;
      m[rr][ic] = *(const float4*)bp;
      vl[rr][ic] = bp[okL ? -1 : 0];
      vr[rr][ic] = bp[okR ? 4 : 0];
    }
  }

  float acc[2][2][4];
  #pragma unroll
  for (int oc = 0; oc < 2; ++oc) {
    const float bb = b3[oc];
    #pragma unroll
    for (int r = 0; r < 2; ++r)
      #pragma unroll
      for (int j = 0; j < 4; ++j) acc[oc][r][j] = bb;
  }
  #pragma unroll
  for (int rr = 0; rr < 4; ++rr) {
    const bool rok = rokf[rr];
    float s[2][6];
    #pragma unroll
    for (int ic = 0; ic < 2; ++ic) {
      s[ic][0] = (rok && okL) ? vl[rr][ic] : 0.f;
      s[ic][1] = rok ? m[rr][ic].x : 0.f;
      s[ic][2] = rok ? m[rr][ic].y : 0.f;
      s[ic][3] = rok ? m[rr][ic].z : 0.f;
      s[ic][4] = rok ? m[rr][ic].w : 0.f;
      s[ic][5] = (rok && okR) ? vr[rr][ic] : 0.f;
    }
    #pragma unroll
    for (int half = 0; half < 2; ++half) {
      if ((half == 0 && rr < 3) || (half == 1 && rr > 0)) {
        const int dy = (half == 0) ? rr : rr - 1;
        #pragma unroll
        for (int oc = 0; oc < 2; ++oc)
          #pragma unroll
          for (int ic = 0; ic < 2; ++ic)
            #pragma unroll
            for (int dx = 0; dx < 3; ++dx) {
              const float w = w3[oc * 18 + ic * 9 + dy * 3 + dx];
              #pragma unroll
              for (int j = 0; j < 4; ++j) acc[oc][half][j] += s[ic][j + dx] * w;
            }
      }
    }
  }
  #pragma unroll
  for (int oc = 0; oc < 2; ++oc)
    #pragma unroll
    for (int r = 0; r < 2; ++r) {
      float4 o;
      o.x = acc[oc][r][0]; o.y = acc[oc][r][1];
      o.z = acc[oc][r][2]; o.w = acc[oc][r][3];
      *(float4*)(c3 + (size_t)oc * H2D * H2D + (size_t)(r0 + r) * H2D + c0) = o;
    }
}

// ---- conv4 + 2x2 maxpool: c3 -> red [1080,1080]. thread: 2 pooled px
__global__ __launch_bounds__(256, 4) void k_conv4pool(
    const float* __restrict__ c3, const float* __restrict__ w4,
    const float* __restrict__ b4, float* __restrict__ red) {
  const int g = blockIdx.x * 256 + threadIdx.x;
  if (g >= 540 * 1080) return;
  const int gx = g % 540, py = g / 540;
  const int c0 = gx * 4, r0 = py * 2;
  const bool okL = gx > 0, okR = gx < 539;

  float4 m[4][2];
  float vl[4][2], vr[4][2];
  bool rokf[4];
  #pragma unroll
  for (int rr = 0; rr < 4; ++rr) {
    const int row = r0 - 1 + rr;
    const bool rok = (unsigned)row < (unsigned)H2D;
    rokf[rr] = rok;
    const size_t rbase = (size_t)(rok ? row : 0) * H2D + c0;
    #pragma unroll
    for (int ic = 0; ic < 2; ++ic) {
      const float* bp = c3 + (size_t)ic * H2D * H2D + rbase;
      m[rr][ic] = *(const float4*)bp;
      vl[rr][ic] = bp[okL ? -1 : 0];
      vr[rr][ic] = bp[okR ? 4 : 0];
    }
  }

  const float bb = b4[0];
  float acc[2][4];
  #pragma unroll
  for (int r = 0; r < 2; ++r)
    #pragma unroll
    for (int j = 0; j < 4; ++j) acc[r][j] = bb;
  #pragma unroll
  for (int rr = 0; rr < 4; ++rr) {
    const bool rok = rokf[rr];
    float s[2][6];
    #pragma unroll
    for (int ic = 0; ic < 2; ++ic) {
      s[ic][0] = (rok && okL) ? vl[rr][ic] : 0.f;
      s[ic][1] = rok ? m[rr][ic].x : 0.f;
      s[ic][2] = rok ? m[rr][ic].y : 0.f;
      s[ic][3] = rok ? m[rr][ic].z : 0.f;
      s[ic][4] = rok ? m[rr][ic].w : 0.f;
      s[ic][5] = (rok && okR) ? vr[rr][ic] : 0.f;
    }
    #pragma unroll
    for (int half = 0; half < 2; ++half) {
      if ((half == 0 && rr < 3) || (half == 1 && rr > 0)) {
        const int dy = (half == 0) ? rr : rr - 1;
        #pragma unroll
        for (int ic = 0; ic < 2; ++ic)
          #pragma unroll
          for (int dx = 0; dx < 3; ++dx) {
            const float w = w4[ic * 9 + dy * 3 + dx];
            #pragma unroll
            for (int j = 0; j < 4; ++j) acc[half][j] += s[ic][j + dx] * w;
          }
      }
    }
  }
  float2 o;
  o.x = fmaxf(fmaxf(acc[0][0], acc[0][1]), fmaxf(acc[1][0], acc[1][1]));
  o.y = fmaxf(fmaxf(acc[0][2], acc[0][3]), fmaxf(acc[1][2], acc[1][3]));
  *(float2*)(red + (size_t)py * FMD + 2 * gx) = o;
}

// ============================================================================
// FALLBACK (ws too small): round-2 fused LDS kernels
// ============================================================================
__global__ __launch_bounds__(256) void k1_backbone1(
    const float* __restrict__ x,
    const float* __restrict__ w1, const float* __restrict__ b1,
    const float* __restrict__ w2, const float* __restrict__ b2,
    float* __restrict__ h2) {
  __shared__ float xs[3][34][36];
  __shared__ float c1s[3][32][36];
  const int tid = threadIdx.x;
  const int bx = blockIdx.x, by = blockIdx.y;
  const int gy0 = by * 30 - 2, gx0 = bx * 30 - 2;
  float W1[81], B1[3];
  #pragma unroll
  for (int i = 0; i < 81; ++i) W1[i] = w1[i];
  #pragma unroll
  for (int i = 0; i < 3; ++i) B1[i] = b1[i];
  for (int l = tid; l < 3 * 34 * 34; l += 256) {
    int c = l / 1156, rem = l % 1156, r = rem / 34, cc = rem % 34;
    int gy = gy0 + r, gx = gx0 + cc;
    float v = 0.f;
    if ((unsigned)gy < IMG && (unsigned)gx < IMG)
      v = x[(size_t)c * IMG * IMG + (size_t)gy * IMG + gx];
    xs[c][r][cc] = v;
  }
  __syncthreads();
  {
    const int r = tid >> 3;
    const int c4 = (tid & 7) << 2;
    float acc[3][4];
    #pragma unroll
    for (int oc = 0; oc < 3; ++oc)
      #pragma unroll
      for (int j = 0; j < 4; ++j) acc[oc][j] = B1[oc];
    #pragma unroll
    for (int ic = 0; ic < 3; ++ic) {
      float xr[3][8];
      #pragma unroll
      for (int dy = 0; dy < 3; ++dy) {
        const float4 q0 = *(const float4*)&xs[ic][r + dy][c4];
        const float4 q1 = *(const float4*)&xs[ic][r + dy][c4 + 4];
        xr[dy][0] = q0.x; xr[dy][1] = q0.y; xr[dy][2] = q0.z; xr[dy][3] = q0.w;
        xr[dy][4] = q1.x; xr[dy][5] = q1.y; xr[dy][6] = q1.z; xr[dy][7] = q1.w;
      }
      #pragma unroll
      for (int oc = 0; oc < 3; ++oc)
        #pragma unroll
        for (int dy = 0; dy < 3; ++dy)
          #pragma unroll
          for (int dx = 0; dx < 3; ++dx) {
            const float w = W1[oc * 27 + ic * 9 + dy * 3 + dx];
            #pragma unroll
            for (int j = 0; j < 4; ++j) acc[oc][j] += xr[dy][j + dx] * w;
          }
    }
    const int gy = by * 30 - 1 + r;
    const bool rOK = (unsigned)gy < IMG;
    const int gxb = bx * 30 - 1 + c4;
    #pragma unroll
    for (int oc = 0; oc < 3; ++oc) {
      float4 o;
      o.x = (rOK && (unsigned)(gxb + 0) < IMG) ? acc[oc][0] : 0.f;
      o.y = (rOK && (unsigned)(gxb + 1) < IMG) ? acc[oc][1] : 0.f;
      o.z = (rOK && (unsigned)(gxb + 2) < IMG) ? acc[oc][2] : 0.f;
      o.w = (rOK && (unsigned)(gxb + 3) < IMG) ? acc[oc][3] : 0.f;
      *(float4*)&c1s[oc][r][c4] = o;
    }
  }
  __syncthreads();
  float W2[54], B2[2];
  #pragma unroll
  for (int i = 0; i < 54; ++i) W2[i] = w2[i];
  B2[0] = b2[0]; B2[1] = b2[1];
  const int ty = tid >> 4, tx = tid & 15;
  if (ty < 15 && tx < 15) {
    float cr[3][4][4];
    #pragma unroll
    for (int ic = 0; ic < 3; ++ic)
      #pragma unroll
      for (int rr = 0; rr < 4; ++rr) {
        const float2 p0 = *(const float2*)&c1s[ic][2 * ty + rr][2 * tx];
        const float2 p1 = *(const float2*)&c1s[ic][2 * ty + rr][2 * tx + 2];
        cr[ic][rr][0] = p0.x; cr[ic][rr][1] = p0.y;
        cr[ic][rr][2] = p1.x; cr[ic][rr][3] = p1.y;
      }
    float m0 = -INFINITY, m1 = -INFINITY;
    #pragma unroll
    for (int sy = 0; sy < 2; ++sy)
      #pragma unroll
      for (int sx = 0; sx < 2; ++sx) {
        float a0 = B2[0], a1 = B2[1];
        #pragma unroll
        for (int ic = 0; ic < 3; ++ic)
          #pragma unroll
          for (int dy = 0; dy < 3; ++dy)
            #pragma unroll
            for (int dx = 0; dx < 3; ++dx) {
              const float v = cr[ic][sy + dy][sx + dx];
              a0 += v * W2[ic * 9 + dy * 3 + dx];
              a1 += v * W2[27 + ic * 9 + dy * 3 + dx];
            }
        m0 = fmaxf(m0, a0);
        m1 = fmaxf(m1, a1);
      }
    const size_t o = (size_t)(by * 15 + ty) * H2D + (bx * 15 + tx);
    h2[o] = m0;
    h2[(size_t)H2D * H2D + o] = m1;
  }
}

__global__ __launch_bounds__(256) void k2_backbone2(
    const float* __restrict__ h2,
    const float* __restrict__ w3, const float* __restrict__ b3,
    const float* __restrict__ w4, const float* __restrict__ b4,
    float* __restrict__ red) {
  __shared__ float hs[2][34][36];
  __shared__ float c3s[2][32][36];
  const int tid = threadIdx.x;
  const int bx = blockIdx.x, by = blockIdx.y;
  const int gy0 = by * 30 - 2, gx0 = bx * 30 - 2;
  float W3[36], B3[2];
  #pragma unroll
  for (int i = 0; i < 36; ++i) W3[i] = w3[i];
  B3[0] = b3[0]; B3[1] = b3[1];
  for (int l = tid; l < 2 * 34 * 34; l += 256) {
    int c = l / 1156, rem = l % 1156, r = rem / 34, cc = rem % 34;
    int gy = gy0 + r, gx = gx0 + cc;
    float v = 0.f;
    if ((unsigned)gy < H2D && (unsigned)gx < H2D)
      v = h2[(size_t)c * H2D * H2D + (size_t)gy * H2D + gx];
    hs[c][r][cc] = v;
  }
  __syncthreads();
  {
    const int r = tid >> 3;
    const int c4 = (tid & 7) << 2;
    float acc[2][4];
    #pragma unroll
    for (int oc = 0; oc < 2; ++oc)
      #pragma unroll
      for (int j = 0; j < 4; ++j) acc[oc][j] = B3[oc];
    #pragma unroll
    for (int ic = 0; ic < 2; ++ic) {
      float xr[3][8];
      #pragma unroll
      for (int dy = 0; dy < 3; ++dy) {
        const float4 q0 = *(const float4*)&hs[ic][r + dy][c4];
        const float4 q1 = *(const float4*)&hs[ic][r + dy][c4 + 4];
        xr[dy][0] = q0.x; xr[dy][1] = q0.y; xr[dy][2] = q0.z; xr[dy][3] = q0.w;
        xr[dy][4] = q1.x; xr[dy][5] = q1.y; xr[dy][6] = q1.z; xr[dy][7] = q1.w;
      }
      #pragma unroll
      for (int oc = 0; oc < 2; ++oc)
        #pragma unroll
        for (int dy = 0; dy < 3; ++dy)
          #pragma unroll
          for (int dx = 0; dx < 3; ++dx) {
            const float w = W3[oc * 18 + ic * 9 + dy * 3 + dx];
            #pragma unroll
            for (int j = 0; j < 4; ++j) acc[oc][j] += xr[dy][j + dx] * w;
          }
    }
    const int gy = by * 30 - 1 + r;
    const bool rOK = (unsigned)gy < H2D;
    const int gxb = bx * 30 - 1 + c4;
    #pragma unroll
    for (int oc = 0; oc < 2; ++oc) {
      float4 o;
      o.x = (rOK && (unsigned)(gxb + 0) < H2D) ? acc[oc][0] : 0.f;
      o.y = (rOK && (unsigned)(gxb + 1) < H2D) ? acc[oc][1] : 0.f;
      o.z = (rOK && (unsigned)(gxb + 2) < H2D) ? acc[oc][2] : 0.f;
      o.w = (rOK && (unsigned)(gxb + 3) < H2D) ? acc[oc][3] : 0.f;
      *(float4*)&c3s[oc][r][c4] = o;
    }
  }
  __syncthreads();
  float W4[18], B4;
  #pragma unroll
  for (int i = 0; i < 18; ++i) W4[i] = w4[i];
  B4 = b4[0];
  const int ty = tid >> 4, tx = tid & 15;
  if (ty < 15 && tx < 15) {
    float cr[2][4][4];
    #pragma unroll
    for (int ic = 0; ic < 2; ++ic)
      #pragma unroll
      for (int rr = 0; rr < 4; ++rr) {
        const float2 p0 = *(const float2*)&c3s[ic][2 * ty + rr][2 * tx];
        const float2 p1 = *(const float2*)&c3s[ic][2 * ty + rr][2 * tx + 2];
        cr[ic][rr][0] = p0.x; cr[ic][rr][1] = p0.y;
        cr[ic][rr][2] = p1.x; cr[ic][rr][3] = p1.y;
      }
    float m = -INFINITY;
    #pragma unroll
    for (int sy = 0; sy < 2; ++sy)
      #pragma unroll
      for (int sx = 0; sx < 2; ++sx) {
        float a = B4;
        #pragma unroll
        for (int ic = 0; ic < 2; ++ic)
          #pragma unroll
          for (int dy = 0; dy < 3; ++dy)
            #pragma unroll
            for (int dx = 0; dx < 3; ++dx)
              a += cr[ic][sy + dy][sx + dx] * W4[ic * 9 + dy * 3 + dx];
        m = fmaxf(m, a);
      }
    red[(size_t)(by * 15 + ty) * FMD + (bx * 15 + tx)] = m;
  }
}

// ============ K3: rpn_conv (50x50, stride 50)  (reduced -> y [2,21,21]) ============
__global__ __launch_bounds__(256) void k3_rpnconv(
    const float* __restrict__ red,
    const float* __restrict__ w, const float* __restrict__ b,
    float* __restrict__ y) {
  __shared__ float part[256];
  const int cell = blockIdx.x;
  const int i = cell / FF, j = cell % FF;
  const int tid = threadIdx.x;
  float a0 = 0.f, a1 = 0.f;
  for (int t = tid; t < 2500; t += 256) {
    int ay = t / 50, ax = t % 50;
    float v = red[(size_t)(50 * i + ay) * FMD + 50 * j + ax];
    a0 += v * w[t];
    a1 += v * w[2500 + t];
  }
  part[tid] = a0;
  __syncthreads();
  for (int s = 128; s > 0; s >>= 1) {
    if (tid < s) part[tid] += part[tid + s];
    __syncthreads();
  }
  if (tid == 0) y[cell] = part[0] + b[0];
  __syncthreads();
  part[tid] = a1;
  __syncthreads();
  for (int s = 128; s > 0; s >>= 1) {
    if (tid < s) part[tid] += part[tid + s];
    __syncthreads();
  }
  if (tid == 0) y[441 + cell] = part[0] + b[1];
}

// ============ K4: rpn heads + faithful masked-select + proposals/rects ============
__global__ __launch_bounds__(512) void k4_select(
    const float* __restrict__ y,
    const float* __restrict__ bbw, const float* __restrict__ bbb,
    const float* __restrict__ clw, const float* __restrict__ clb,
    float* __restrict__ props_out, int* __restrict__ rects,
    unsigned* __restrict__ pooled_m) {
  __shared__ float ys[2][23][23];
  __shared__ unsigned char flag[6][441];
  __shared__ short pos[6][20];
  __shared__ int cnt[6];
  __shared__ int selT[20];
  __shared__ float offv[20], anchv[20];
  const int tid = threadIdx.x;
  for (int l = tid; l < 2 * 23 * 23; l += 512) ((float*)ys)[l] = 0.f;
  __syncthreads();
  for (int l = tid; l < 2 * 441; l += 512) {
    int c = l / 441, p = l % 441;
    ys[c][p / 21 + 1][p % 21 + 1] = y[l];
  }
  __syncthreads();
  for (int l = tid; l < 6 * 441; l += 512) {
    int a = l / 441, p = l % 441, i = p / 21, j = p % 21;
    float v = clb[a];
    #pragma unroll
    for (int c2 = 0; c2 < 2; c2++)
      #pragma unroll
      for (int dy = 0; dy < 3; dy++)
        #pragma unroll
        for (int dx = 0; dx < 3; dx++)
          v += ys[c2][i + dy][j + dx] * clw[a * 18 + c2 * 9 + dy * 3 + dx];
    flag[a][p] = (tanhf(v) > 0.95f) ? 1 : 0;
  }
  __syncthreads();
  if (tid < 6) {
    int c = 0;
    for (int p = 0; p < 441; p++)
      if (flag[tid][p]) {
        if (c < 20) pos[tid][c] = (short)p;
        c++;
      }
    cnt[tid] = c;
  }
  __syncthreads();
  if (tid == 0) {
    int s = 0;
    for (int g = 0; g < 24 && s < 20; g++) {
      int a = g >> 2;
      int take = cnt[a] < 20 - s ? cnt[a] : 20 - s;
      for (int r = 0; r < take; r++) selT[s++] = g * 441 + (int)pos[a][r];
    }
    if (s < 20) {
      for (int t = 0; t < 10584 && s < 20; t++) {
        int a = t / 1764, p = t % 441;
        if (!flag[a][p]) selT[s++] = t;
      }
    }
  }
  __syncthreads();
  if (tid < 20) {
    int t = selT[tid];
    int ch = t / 441, p = t % 441, i = p / 21, j = p % 21;
    int a = ch >> 2, c = ch & 3;
    float v = bbb[ch];
    #pragma unroll
    for (int c2 = 0; c2 < 2; c2++)
      #pragma unroll
      for (int dy = 0; dy < 3; dy++)
        #pragma unroll
        for (int dx = 0; dx < 3; dx++)
          v += ys[c2][i + dy][j + dx] * bbw[ch * 18 + c2 * 9 + dy * 3 + dx];
    offv[tid] = v;
    float sz = (a < 3) ? 1.f : 2.f;
    int am = a % 3;
    float ar = (am == 0) ? 0.5f : (am == 1 ? 1.f : 2.f);
    float base;
    if (c == 0) base = 0.f;
    else if (c == 1) base = sz * -(ar - 1.f) * 0.5f;
    else if (c == 2) base = sz;
    else base = sz * (1.f + (ar - 1.f) * 0.5f);
    anchv[tid] = base + ((c & 1) ? (float)j : (float)i);
  }
  __syncthreads();
  if (tid < 5) {
    int k = tid;
    float o0 = offv[4 * k], o1 = offv[4 * k + 1], o2 = offv[4 * k + 2], o3 = offv[4 * k + 3];
    float a0 = anchv[4 * k], a2 = anchv[4 * k + 2], a3 = anchv[4 * k + 3];
    float p0 = fminf(fmaxf(o0 + a0 - a2 * 0.5f, 0.f), 21.f) * 50.f;
    float p1 = fminf(fmaxf(o1 - a3 * 0.5f, 0.f), 21.f) * 50.f;
    float p2 = fminf(fmaxf(o2 + a0 + a2 * 0.5f, 0.f), 21.f) * 50.f;
    float p3 = fminf(fmaxf(o3 + a3 * 0.5f, 0.f), 21.f) * 50.f;
    props_out[k * 4 + 0] = p0;
    props_out[k * 4 + 1] = p1;
    props_out[k * 4 + 2] = p2;
    props_out[k * 4 + 3] = p3;
    float x1 = rintf(p0), y1 = rintf(p1), x2 = rintf(p2), y2 = rintf(p3);
    float bwf = fmaxf(x2 - x1 + 1.f, 1.f) * 0.5f;
    float bhf = fmaxf(y2 - y1 + 1.f, 1.f) * 0.5f;
    for (int ph = 0; ph < 2; ph++)
      for (int pw = 0; pw < 2; pw++) {
        int hsv = (int)fminf(fmaxf(floorf((float)ph * bhf) + y1, 0.f), 1080.f);
        int hev = (int)fminf(fmaxf(ceilf((float)(ph + 1) * bhf) + y1, 0.f), 1080.f);
        int wsv = (int)fminf(fmaxf(floorf((float)pw * bwf) + x1, 0.f), 1080.f);
        int wev = (int)fminf(fmaxf(ceilf((float)(pw + 1) * bwf) + x1, 0.f), 1080.f);
        int idx = k * 4 + ph * 2 + pw;
        rects[idx * 4 + 0] = hsv;
        rects[idx * 4 + 1] = hev;
        rects[idx * 4 + 2] = wsv;
        rects[idx * 4 + 3] = wev;
      }
  }
  if (tid >= 32 && tid < 52) pooled_m[tid - 32] = 0x007FFFFFu;  // mapped(-inf)
}

// ============ K5: RoI max pool (atomicMax on order-preserving uint map) ============
__global__ __launch_bounds__(256) void k5_roipool(
    const float* __restrict__ red, const int* __restrict__ rects,
    unsigned* __restrict__ pooled_m) {
  const int cell = blockIdx.x;
  const int hs = rects[cell * 4 + 0], he = rects[cell * 4 + 1];
  const int wss = rects[cell * 4 + 2], wee = rects[cell * 4 + 3];
  const int nr = he - hs;
  if (nr <= 0 || wee <= wss) return;
  const int slice = blockIdx.y, nslice = gridDim.y;
  const int r0 = hs + (int)((long)nr * slice / nslice);
  const int r1 = hs + (int)((long)nr * (slice + 1) / nslice);
  float m = -INFINITY;
  for (int r = r0; r < r1; r++)
    for (int c = wss + (int)threadIdx.x; c < wee; c += 256)
      m = fmaxf(m, red[(size_t)r * FMD + c]);
  __shared__ float part[256];
  part[threadIdx.x] = m;
  __syncthreads();
  for (int s = 128; s > 0; s >>= 1) {
    if ((int)threadIdx.x < s) part[threadIdx.x] = fmaxf(part[threadIdx.x], part[threadIdx.x + s]);
    __syncthreads();
  }
  if (threadIdx.x == 0 && part[0] > -INFINITY) {
    unsigned u = __float_as_uint(part[0]);
    u = (u & 0x80000000u) ? ~u : (u | 0x80000000u);
    atomicMax(&pooled_m[cell], u);
  }
}

// ============ K6: fc / box / cls heads -> d_out (30 floats) ============
__global__ void k6_heads(
    const unsigned* __restrict__ pooled_m, const float* __restrict__ props,
    const float* __restrict__ fcw, const float* __restrict__ fcb,
    const float* __restrict__ bxw, const float* __restrict__ bxb,
    const float* __restrict__ clw, const float* __restrict__ clb,
    float* __restrict__ out) {
  if (threadIdx.x != 0 || blockIdx.x != 0) return;
  float pooled[5][4];
  for (int i = 0; i < 20; i++) {
    unsigned u = pooled_m[i];
    float f = (u & 0x80000000u) ? __uint_as_float(u ^ 0x80000000u) : __uint_as_float(~u);
    if (!isfinite(f)) f = 0.f;
    pooled[i / 4][i % 4] = f;
  }
  for (int k = 0; k < 5; k++) {
    float fc[12];
    for (int m = 0; m < 12; m++) {
      float v = fcb[m];
      for (int n = 0; n < 4; n++) v += pooled[k][n] * fcw[m * 4 + n];
      fc[m] = v;
    }
    float bo[4];
    for (int c = 0; c < 4; c++) {
      float v = bxb[c];
      for (int m = 0; m < 12; m++) v += fc[m] * bxw[c * 12 + m];
      bo[c] = v;
    }
    float p0 = props[k * 4], p1 = props[k * 4 + 1], p2 = props[k * 4 + 2], p3 = props[k * 4 + 3];
    out[k * 4 + 0] = fminf(fmaxf(p0 + bo[0] - bo[2] * 0.5f, 0.f), 3.f);
    out[k * 4 + 1] = fminf(fmaxf(p1 - bo[3] * 0.5f, 0.f), 1.f);
    out[k * 4 + 2] = fminf(fmaxf(p2 + bo[0] + bo[2] * 0.5f, 0.f), 3.f);
    out[k * 4 + 3] = fminf(fmaxf(p3 + bo[3] * 0.5f, 0.f), 1.f);
    float l0 = clb[0], l1 = clb[1];
    for (int m = 0; m < 12; m++) {
      l0 += fc[m] * clw[m];
      l1 += fc[m] * clw[12 + m];
    }
    float mx = fmaxf(l0, l1);
    float e0 = expf(l0 - mx), e1 = expf(l1 - mx);
    out[20 + k * 2 + 0] = e0 / (e0 + e1);
    out[20 + k * 2 + 1] = e1 / (e0 + e1);
  }
}

extern "C" void kernel_launch(void* const* d_in, const int* in_sizes, int n_in,
                              void* d_out, int out_size, void* d_ws, size_t ws_size,
                              hipStream_t stream) {
  const float* x   = (const float*)d_in[0];
  const float* w1  = (const float*)d_in[1];
  const float* b1  = (const float*)d_in[2];
  const float* w2  = (const float*)d_in[3];
  const float* b2  = (const float*)d_in[4];
  const float* w3  = (const float*)d_in[5];
  const float* b3  = (const float*)d_in[6];
  const float* w4  = (const float*)d_in[7];
  const float* b4  = (const float*)d_in[8];
  const float* rw  = (const float*)d_in[9];
  const float* rb  = (const float*)d_in[10];
  const float* bbw = (const float*)d_in[11];
  const float* bbb = (const float*)d_in[12];
  const float* clw = (const float*)d_in[13];
  const float* clb = (const float*)d_in[14];
  const float* fcw = (const float*)d_in[15];
  const float* fcb = (const float*)d_in[16];
  const float* bxw = (const float*)d_in[17];
  const float* bxb = (const float*)d_in[18];
  const float* c2w = (const float*)d_in[19];
  const float* c2b = (const float*)d_in[20];

  char* wsb = (char*)d_ws;

  if (ws_size >= 160000000ull) {
    // split path: c1(bf16) 0..111,974,400 | h2 | red | small; c3 aliases c1
    u16*   c1u = (u16*)wsb;
    float* h2  = (float*)(wsb + 111974400);
    float* c3  = (float*)wsb;
    float* red = (float*)(wsb + 149299200);
    float* yv  = (float*)(wsb + 153964800);
    float* props = yv + 882;
    int*   rects = (int*)(props + 20);
    unsigned* pooled_m = (unsigned*)(rects + 80);

    k_conv1    <<<9113, 256, 0, stream>>>(x, w1, b1, c1u);
    k_conv2pool<<<9113, 256, 0, stream>>>(c1u, w2, b2, h2);
    k_conv3    <<<2279, 256, 0, stream>>>(h2, w3, b3, c3);
    k_conv4pool<<<2279, 256, 0, stream>>>(c3, w4, b4, red);
    k3_rpnconv<<<441, 256, 0, stream>>>(red, rw, rb, yv);
    k4_select<<<1, 512, 0, stream>>>(yv, bbw, bbb, clw, clb, props, rects, pooled_m);
    k5_roipool<<<dim3(20, 16), 256, 0, stream>>>(red, rects, pooled_m);
    k6_heads<<<1, 64, 0, stream>>>(pooled_m, props, fcw, fcb, bxw, bxb, c2w, c2b,
                                   (float*)d_out);
  } else {
    // fallback: round-2 fused path (42 MB workspace)
    float* ws = (float*)d_ws;
    float* h2 = ws;
    float* red = ws + 9331200;
    float* yv = ws + 10497600;
    float* props = ws + 10498482;
    int* rects = (int*)(ws + 10498502);
    unsigned* pooled_m = (unsigned*)(ws + 10498582);

    k1_backbone1<<<dim3(144, 144), 256, 0, stream>>>(x, w1, b1, w2, b2, h2);
    k2_backbone2<<<dim3(72, 72), 256, 0, stream>>>(h2, w3, b3, w4, b4, red);
    k3_rpnconv<<<441, 256, 0, stream>>>(red, rw, rb, yv);
    k4_select<<<1, 512, 0, stream>>>(yv, bbw, bbb, clw, clb, props, rects, pooled_m);
    k5_roipool<<<dim3(20, 16), 256, 0, stream>>>(red, rects, pooled_m);
    k6_heads<<<1, 64, 0, stream>>>(pooled_m, props, fcw, fcb, bxw, bxb, c2w, c2b,
                                   (float*)d_out);
  }
}

// Round 8
// 224.581 us; speedup vs baseline: 1.9193x; 1.0658x over previous
//
#include <hip/hip_runtime.h>
#include <math.h>

#define IMG 4320
#define H2D 2160
#define FMD 1080
#define FF 21

typedef unsigned short u16;

__device__ __forceinline__ float bf2f(u16 h) {
  return __uint_as_float(((unsigned)h) << 16);
}
__device__ __forceinline__ u16 f2bf(float f) {  // RTNE
  unsigned u = __float_as_uint(f);
  unsigned r = 0x7FFFu + ((u >> 16) & 1u);
  return (u16)((u + r) >> 16);
}

// ============================================================================
// SPLIT BACKBONE, big register tiles + high VGPR cap:
//  - all window loads issued up front from clamped in-bounds addresses
//  - __launch_bounds__(256,2) -> VGPR cap 256 so staging stays in registers
//  - template<REDGE>: interior blocks have zero row-edge selects
// ============================================================================

// ---- conv1: x[3,4320,4320] -> c1 bf16. thread: 4 rows x 4 cols ----
template<bool REDGE>
__device__ __forceinline__ void conv1_body(
    const int gx, const int gy,
    const float* __restrict__ x, const float* __restrict__ w1,
    const float* __restrict__ b1, u16* __restrict__ c1) {
  const int c0 = gx * 4, r0 = gy * 4;
  const bool okL = gx > 0, okR = gx < 1079;
  float s[6][3][6];
  // phase 1: all 54 loads
  #pragma unroll
  for (int rr = 0; rr < 6; ++rr) {
    const int row = r0 - 1 + rr;
    const int rowc = REDGE ? (row < 0 ? 0 : (row > IMG - 1 ? IMG - 1 : row)) : row;
    const size_t rbase = (size_t)rowc * IMG + c0;
    #pragma unroll
    for (int ic = 0; ic < 3; ++ic) {
      const float* bp = x + (size_t)ic * IMG * IMG + rbase;
      const float4 q = *(const float4*)bp;
      s[rr][ic][1] = q.x; s[rr][ic][2] = q.y; s[rr][ic][3] = q.z; s[rr][ic][4] = q.w;
      s[rr][ic][0] = bp[okL ? -1 : 0];
      s[rr][ic][5] = bp[okR ? 4 : 0];
    }
  }
  // phase 2: selects
  #pragma unroll
  for (int rr = 0; rr < 6; ++rr) {
    const bool rok = REDGE ? ((unsigned)(r0 - 1 + rr) < (unsigned)IMG) : true;
    #pragma unroll
    for (int ic = 0; ic < 3; ++ic) {
      if (REDGE) {
        #pragma unroll
        for (int j = 0; j < 6; ++j) s[rr][ic][j] = rok ? s[rr][ic][j] : 0.f;
      }
      s[rr][ic][0] = okL ? s[rr][ic][0] : 0.f;
      s[rr][ic][5] = okR ? s[rr][ic][5] : 0.f;
    }
  }
  // FMA
  float acc[3][4][4];
  #pragma unroll
  for (int oc = 0; oc < 3; ++oc) {
    const float bb = b1[oc];
    #pragma unroll
    for (int r = 0; r < 4; ++r)
      #pragma unroll
      for (int j = 0; j < 4; ++j) acc[oc][r][j] = bb;
  }
  #pragma unroll
  for (int oc = 0; oc < 3; ++oc)
    #pragma unroll
    for (int ic = 0; ic < 3; ++ic)
      #pragma unroll
      for (int dy = 0; dy < 3; ++dy)
        #pragma unroll
        for (int dx = 0; dx < 3; ++dx) {
          const float w = w1[oc * 27 + ic * 9 + dy * 3 + dx];
          #pragma unroll
          for (int r = 0; r < 4; ++r)
            #pragma unroll
            for (int j = 0; j < 4; ++j)
              acc[oc][r][j] += s[r + dy][ic][j + dx] * w;
        }
  #pragma unroll
  for (int oc = 0; oc < 3; ++oc)
    #pragma unroll
    for (int r = 0; r < 4; ++r) {
      ushort4 h;
      h.x = f2bf(acc[oc][r][0]); h.y = f2bf(acc[oc][r][1]);
      h.z = f2bf(acc[oc][r][2]); h.w = f2bf(acc[oc][r][3]);
      *(ushort4*)(c1 + (size_t)oc * IMG * IMG + (size_t)(r0 + r) * IMG + c0) = h;
    }
}

__global__ __launch_bounds__(256, 2) void k_conv1(
    const float* __restrict__ x, const float* __restrict__ w1,
    const float* __restrict__ b1, u16* __restrict__ c1) {
  const int g = blockIdx.x * 256 + threadIdx.x;
  if (g >= 1080 * 1080) return;
  const int gx = g % 1080, gy = g / 1080;
  const int gy_min = (blockIdx.x * 256) / 1080;
  const int gy_max = (blockIdx.x * 256 + 255) / 1080;
  if (gy_min == 0 || gy_max >= 1079) conv1_body<true>(gx, gy, x, w1, b1, c1);
  else                               conv1_body<false>(gx, gy, x, w1, b1, c1);
}

// ---- conv2 + pool: c1 bf16 -> h2 [2,2160,2160]. thread: 2x2 pooled ----
template<bool REDGE>
__device__ __forceinline__ void conv2_body(
    const int gx, const int gy,
    const u16* __restrict__ c1, const float* __restrict__ w2,
    const float* __restrict__ b2, float* __restrict__ h2) {
  const int c0 = gx * 4, r0 = gy * 4;
  const bool okL = gx > 0, okR = gx < 1079;
  ushort4 mv[6][3];
  u16 lv[6][3], rv[6][3];
  #pragma unroll
  for (int rr = 0; rr < 6; ++rr) {
    const int row = r0 - 1 + rr;
    const int rowc = REDGE ? (row < 0 ? 0 : (row > IMG - 1 ? IMG - 1 : row)) : row;
    const size_t rbase = (size_t)rowc * IMG + c0;
    #pragma unroll
    for (int ic = 0; ic < 3; ++ic) {
      const u16* bp = c1 + (size_t)ic * IMG * IMG + rbase;
      mv[rr][ic] = *(const ushort4*)bp;
      lv[rr][ic] = bp[okL ? -1 : 0];
      rv[rr][ic] = bp[okR ? 4 : 0];
    }
  }
  float s[6][3][6];
  #pragma unroll
  for (int rr = 0; rr < 6; ++rr) {
    const bool rok = REDGE ? ((unsigned)(r0 - 1 + rr) < (unsigned)IMG) : true;
    #pragma unroll
    for (int ic = 0; ic < 3; ++ic) {
      s[rr][ic][0] = (okL && rok) ? bf2f(lv[rr][ic]) : 0.f;
      s[rr][ic][1] = bf2f(mv[rr][ic].x);
      s[rr][ic][2] = bf2f(mv[rr][ic].y);
      s[rr][ic][3] = bf2f(mv[rr][ic].z);
      s[rr][ic][4] = bf2f(mv[rr][ic].w);
      s[rr][ic][5] = (okR && rok) ? bf2f(rv[rr][ic]) : 0.f;
      if (REDGE) {
        #pragma unroll
        for (int j = 1; j < 5; ++j) s[rr][ic][j] = rok ? s[rr][ic][j] : 0.f;
      }
    }
  }
  float pm[2][2][2];
  #pragma unroll
  for (int oc = 0; oc < 2; ++oc)
    #pragma unroll
    for (int a = 0; a < 2; ++a)
      #pragma unroll
      for (int b = 0; b < 2; ++b) pm[oc][a][b] = -INFINITY;
  #pragma unroll
  for (int cr = 0; cr < 4; ++cr) {
    float v[2][4];
    #pragma unroll
    for (int oc = 0; oc < 2; ++oc) {
      const float bb = b2[oc];
      #pragma unroll
      for (int cc = 0; cc < 4; ++cc) v[oc][cc] = bb;
    }
    #pragma unroll
    for (int oc = 0; oc < 2; ++oc)
      #pragma unroll
      for (int ic = 0; ic < 3; ++ic)
        #pragma unroll
        for (int dy = 0; dy < 3; ++dy)
          #pragma unroll
          for (int dx = 0; dx < 3; ++dx) {
            const float w = w2[oc * 27 + ic * 9 + dy * 3 + dx];
            #pragma unroll
            for (int cc = 0; cc < 4; ++cc)
              v[oc][cc] += s[cr + dy][ic][cc + dx] * w;
          }
    #pragma unroll
    for (int oc = 0; oc < 2; ++oc)
      #pragma unroll
      for (int cc = 0; cc < 4; ++cc)
        pm[oc][cr >> 1][cc >> 1] = fmaxf(pm[oc][cr >> 1][cc >> 1], v[oc][cc]);
  }
  #pragma unroll
  for (int oc = 0; oc < 2; ++oc)
    #pragma unroll
    for (int rp = 0; rp < 2; ++rp) {
      float2 o;
      o.x = pm[oc][rp][0];
      o.y = pm[oc][rp][1];
      *(float2*)(h2 + (size_t)oc * H2D * H2D + (size_t)(gy * 2 + rp) * H2D + gx * 2) = o;
    }
}

__global__ __launch_bounds__(256, 2) void k_conv2pool(
    const u16* __restrict__ c1, const float* __restrict__ w2,
    const float* __restrict__ b2, float* __restrict__ h2) {
  const int g = blockIdx.x * 256 + threadIdx.x;
  if (g >= 1080 * 1080) return;
  const int gx = g % 1080, gy = g / 1080;
  const int gy_min = (blockIdx.x * 256) / 1080;
  const int gy_max = (blockIdx.x * 256 + 255) / 1080;
  if (gy_min == 0 || gy_max >= 1079) conv2_body<true>(gx, gy, c1, w2, b2, h2);
  else                               conv2_body<false>(gx, gy, c1, w2, b2, h2);
}

// ---- conv3: h2 -> c3 [2,2160,2160]. thread: 4 rows x 4 cols ----
template<bool REDGE>
__device__ __forceinline__ void conv3_body(
    const int gx, const int gy,
    const float* __restrict__ h2, const float* __restrict__ w3,
    const float* __restrict__ b3, float* __restrict__ c3) {
  const int c0 = gx * 4, r0 = gy * 4;
  const bool okL = gx > 0, okR = gx < 539;
  float s[6][2][6];
  #pragma unroll
  for (int rr = 0; rr < 6; ++rr) {
    const int row = r0 - 1 + rr;
    const int rowc = REDGE ? (row < 0 ? 0 : (row > H2D - 1 ? H2D - 1 : row)) : row;
    const size_t rbase = (size_t)rowc * H2D + c0;
    #pragma unroll
    for (int ic = 0; ic < 2; ++ic) {
      const float* bp = h2 + (size_t)ic * H2D * H2D + rbase;
      const float4 q = *(const float4*)bp;
      s[rr][ic][1] = q.x; s[rr][ic][2] = q.y; s[rr][ic][3] = q.z; s[rr][ic][4] = q.w;
      s[rr][ic][0] = bp[okL ? -1 : 0];
      s[rr][ic][5] = bp[okR ? 4 : 0];
    }
  }
  #pragma unroll
  for (int rr = 0; rr < 6; ++rr) {
    const bool rok = REDGE ? ((unsigned)(r0 - 1 + rr) < (unsigned)H2D) : true;
    #pragma unroll
    for (int ic = 0; ic < 2; ++ic) {
      if (REDGE) {
        #pragma unroll
        for (int j = 0; j < 6; ++j) s[rr][ic][j] = rok ? s[rr][ic][j] : 0.f;
      }
      s[rr][ic][0] = okL ? s[rr][ic][0] : 0.f;
      s[rr][ic][5] = okR ? s[rr][ic][5] : 0.f;
    }
  }
  float acc[2][4][4];
  #pragma unroll
  for (int oc = 0; oc < 2; ++oc) {
    const float bb = b3[oc];
    #pragma unroll
    for (int r = 0; r < 4; ++r)
      #pragma unroll
      for (int j = 0; j < 4; ++j) acc[oc][r][j] = bb;
  }
  #pragma unroll
  for (int oc = 0; oc < 2; ++oc)
    #pragma unroll
    for (int ic = 0; ic < 2; ++ic)
      #pragma unroll
      for (int dy = 0; dy < 3; ++dy)
        #pragma unroll
        for (int dx = 0; dx < 3; ++dx) {
          const float w = w3[oc * 18 + ic * 9 + dy * 3 + dx];
          #pragma unroll
          for (int r = 0; r < 4; ++r)
            #pragma unroll
            for (int j = 0; j < 4; ++j)
              acc[oc][r][j] += s[r + dy][ic][j + dx] * w;
        }
  #pragma unroll
  for (int oc = 0; oc < 2; ++oc)
    #pragma unroll
    for (int r = 0; r < 4; ++r) {
      float4 o;
      o.x = acc[oc][r][0]; o.y = acc[oc][r][1];
      o.z = acc[oc][r][2]; o.w = acc[oc][r][3];
      *(float4*)(c3 + (size_t)oc * H2D * H2D + (size_t)(r0 + r) * H2D + c0) = o;
    }
}

__global__ __launch_bounds__(256, 2) void k_conv3(
    const float* __restrict__ h2, const float* __restrict__ w3,
    const float* __restrict__ b3, float* __restrict__ c3) {
  const int g = blockIdx.x * 256 + threadIdx.x;
  if (g >= 540 * 540) return;
  const int gx = g % 540, gy = g / 540;
  const int gy_min = (blockIdx.x * 256) / 540;
  const int gy_max = (blockIdx.x * 256 + 255) / 540;
  if (gy_min == 0 || gy_max >= 539) conv3_body<true>(gx, gy, h2, w3, b3, c3);
  else                              conv3_body<false>(gx, gy, h2, w3, b3, c3);
}

// ---- conv4 + pool: c3 -> red [1080,1080]. thread: 2x2 pooled ----
template<bool REDGE>
__device__ __forceinline__ void conv4_body(
    const int gx, const int gy,
    const float* __restrict__ c3, const float* __restrict__ w4,
    const float* __restrict__ b4, float* __restrict__ red) {
  const int c0 = gx * 4, r0 = gy * 4;
  const bool okL = gx > 0, okR = gx < 539;
  float s[6][2][6];
  #pragma unroll
  for (int rr = 0; rr < 6; ++rr) {
    const int row = r0 - 1 + rr;
    const int rowc = REDGE ? (row < 0 ? 0 : (row > H2D - 1 ? H2D - 1 : row)) : row;
    const size_t rbase = (size_t)rowc * H2D + c0;
    #pragma unroll
    for (int ic = 0; ic < 2; ++ic) {
      const float* bp = c3 + (size_t)ic * H2D * H2D + rbase;
      const float4 q = *(const float4*)bp;
      s[rr][ic][1] = q.x; s[rr][ic][2] = q.y; s[rr][ic][3] = q.z; s[rr][ic][4] = q.w;
      s[rr][ic][0] = bp[okL ? -1 : 0];
      s[rr][ic][5] = bp[okR ? 4 : 0];
    }
  }
  #pragma unroll
  for (int rr = 0; rr < 6; ++rr) {
    const bool rok = REDGE ? ((unsigned)(r0 - 1 + rr) < (unsigned)H2D) : true;
    #pragma unroll
    for (int ic = 0; ic < 2; ++ic) {
      if (REDGE) {
        #pragma unroll
        for (int j = 0; j < 6; ++j) s[rr][ic][j] = rok ? s[rr][ic][j] : 0.f;
      }
      s[rr][ic][0] = okL ? s[rr][ic][0] : 0.f;
      s[rr][ic][5] = okR ? s[rr][ic][5] : 0.f;
    }
  }
  float pm[2][2];
  pm[0][0] = pm[0][1] = pm[1][0] = pm[1][1] = -INFINITY;
  const float bb = b4[0];
  #pragma unroll
  for (int cr = 0; cr < 4; ++cr) {
    float v[4];
    #pragma unroll
    for (int cc = 0; cc < 4; ++cc) v[cc] = bb;
    #pragma unroll
    for (int ic = 0; ic < 2; ++ic)
      #pragma unroll
      for (int dy = 0; dy < 3; ++dy)
        #pragma unroll
        for (int dx = 0; dx < 3; ++dx) {
          const float w = w4[ic * 9 + dy * 3 + dx];
          #pragma unroll
          for (int cc = 0; cc < 4; ++cc)
            v[cc] += s[cr + dy][ic][cc + dx] * w;
        }
    #pragma unroll
    for (int cc = 0; cc < 4; ++cc)
      pm[cr >> 1][cc >> 1] = fmaxf(pm[cr >> 1][cc >> 1], v[cc]);
  }
  #pragma unroll
  for (int rp = 0; rp < 2; ++rp) {
    float2 o;
    o.x = pm[rp][0];
    o.y = pm[rp][1];
    *(float2*)(red + (size_t)(gy * 2 + rp) * FMD + gx * 2) = o;
  }
}

__global__ __launch_bounds__(256, 2) void k_conv4pool(
    const float* __restrict__ c3, const float* __restrict__ w4,
    const float* __restrict__ b4, float* __restrict__ red) {
  const int g = blockIdx.x * 256 + threadIdx.x;
  if (g >= 540 * 540) return;
  const int gx = g % 540, gy = g / 540;
  const int gy_min = (blockIdx.x * 256) / 540;
  const int gy_max = (blockIdx.x * 256 + 255) / 540;
  if (gy_min == 0 || gy_max >= 539) conv4_body<true>(gx, gy, c3, w4, b4, red);
  else                              conv4_body<false>(gx, gy, c3, w4, b4, red);
}

// ============================================================================
// FALLBACK (ws too small): round-2 fused LDS kernels
// ============================================================================
__global__ __launch_bounds__(256) void k1_backbone1(
    const float* __restrict__ x,
    const float* __restrict__ w1, const float* __restrict__ b1,
    const float* __restrict__ w2, const float* __restrict__ b2,
    float* __restrict__ h2) {
  __shared__ float xs[3][34][36];
  __shared__ float c1s[3][32][36];
  const int tid = threadIdx.x;
  const int bx = blockIdx.x, by = blockIdx.y;
  const int gy0 = by * 30 - 2, gx0 = bx * 30 - 2;
  float W1[81], B1[3];
  #pragma unroll
  for (int i = 0; i < 81; ++i) W1[i] = w1[i];
  #pragma unroll
  for (int i = 0; i < 3; ++i) B1[i] = b1[i];
  for (int l = tid; l < 3 * 34 * 34; l += 256) {
    int c = l / 1156, rem = l % 1156, r = rem / 34, cc = rem % 34;
    int gy = gy0 + r, gx = gx0 + cc;
    float v = 0.f;
    if ((unsigned)gy < IMG && (unsigned)gx < IMG)
      v = x[(size_t)c * IMG * IMG + (size_t)gy * IMG + gx];
    xs[c][r][cc] = v;
  }
  __syncthreads();
  {
    const int r = tid >> 3;
    const int c4 = (tid & 7) << 2;
    float acc[3][4];
    #pragma unroll
    for (int oc = 0; oc < 3; ++oc)
      #pragma unroll
      for (int j = 0; j < 4; ++j) acc[oc][j] = B1[oc];
    #pragma unroll
    for (int ic = 0; ic < 3; ++ic) {
      float xr[3][8];
      #pragma unroll
      for (int dy = 0; dy < 3; ++dy) {
        const float4 q0 = *(const float4*)&xs[ic][r + dy][c4];
        const float4 q1 = *(const float4*)&xs[ic][r + dy][c4 + 4];
        xr[dy][0] = q0.x; xr[dy][1] = q0.y; xr[dy][2] = q0.z; xr[dy][3] = q0.w;
        xr[dy][4] = q1.x; xr[dy][5] = q1.y; xr[dy][6] = q1.z; xr[dy][7] = q1.w;
      }
      #pragma unroll
      for (int oc = 0; oc < 3; ++oc)
        #pragma unroll
        for (int dy = 0; dy < 3; ++dy)
          #pragma unroll
          for (int dx = 0; dx < 3; ++dx) {
            const float w = W1[oc * 27 + ic * 9 + dy * 3 + dx];
            #pragma unroll
            for (int j = 0; j < 4; ++j) acc[oc][j] += xr[dy][j + dx] * w;
          }
    }
    const int gy = by * 30 - 1 + r;
    const bool rOK = (unsigned)gy < IMG;
    const int gxb = bx * 30 - 1 + c4;
    #pragma unroll
    for (int oc = 0; oc < 3; ++oc) {
      float4 o;
      o.x = (rOK && (unsigned)(gxb + 0) < IMG) ? acc[oc][0] : 0.f;
      o.y = (rOK && (unsigned)(gxb + 1) < IMG) ? acc[oc][1] : 0.f;
      o.z = (rOK && (unsigned)(gxb + 2) < IMG) ? acc[oc][2] : 0.f;
      o.w = (rOK && (unsigned)(gxb + 3) < IMG) ? acc[oc][3] : 0.f;
      *(float4*)&c1s[oc][r][c4] = o;
    }
  }
  __syncthreads();
  float W2[54], B2[2];
  #pragma unroll
  for (int i = 0; i < 54; ++i) W2[i] = w2[i];
  B2[0] = b2[0]; B2[1] = b2[1];
  const int ty = tid >> 4, tx = tid & 15;
  if (ty < 15 && tx < 15) {
    float cr[3][4][4];
    #pragma unroll
    for (int ic = 0; ic < 3; ++ic)
      #pragma unroll
      for (int rr = 0; rr < 4; ++rr) {
        const float2 p0 = *(const float2*)&c1s[ic][2 * ty + rr][2 * tx];
        const float2 p1 = *(const float2*)&c1s[ic][2 * ty + rr][2 * tx + 2];
        cr[ic][rr][0] = p0.x; cr[ic][rr][1] = p0.y;
        cr[ic][rr][2] = p1.x; cr[ic][rr][3] = p1.y;
      }
    float m0 = -INFINITY, m1 = -INFINITY;
    #pragma unroll
    for (int sy = 0; sy < 2; ++sy)
      #pragma unroll
      for (int sx = 0; sx < 2; ++sx) {
        float a0 = B2[0], a1 = B2[1];
        #pragma unroll
        for (int ic = 0; ic < 3; ++ic)
          #pragma unroll
          for (int dy = 0; dy < 3; ++dy)
            #pragma unroll
            for (int dx = 0; dx < 3; ++dx) {
              const float v = cr[ic][sy + dy][sx + dx];
              a0 += v * W2[ic * 9 + dy * 3 + dx];
              a1 += v * W2[27 + ic * 9 + dy * 3 + dx];
            }
        m0 = fmaxf(m0, a0);
        m1 = fmaxf(m1, a1);
      }
    const size_t o = (size_t)(by * 15 + ty) * H2D + (bx * 15 + tx);
    h2[o] = m0;
    h2[(size_t)H2D * H2D + o] = m1;
  }
}

__global__ __launch_bounds__(256) void k2_backbone2(
    const float* __restrict__ h2,
    const float* __restrict__ w3, const float* __restrict__ b3,
    const float* __restrict__ w4, const float* __restrict__ b4,
    float* __restrict__ red) {
  __shared__ float hs[2][34][36];
  __shared__ float c3s[2][32][36];
  const int tid = threadIdx.x;
  const int bx = blockIdx.x, by = blockIdx.y;
  const int gy0 = by * 30 - 2, gx0 = bx * 30 - 2;
  float W3[36], B3[2];
  #pragma unroll
  for (int i = 0; i < 36; ++i) W3[i] = w3[i];
  B3[0] = b3[0]; B3[1] = b3[1];
  for (int l = tid; l < 2 * 34 * 34; l += 256) {
    int c = l / 1156, rem = l % 1156, r = rem / 34, cc = rem % 34;
    int gy = gy0 + r, gx = gx0 + cc;
    float v = 0.f;
    if ((unsigned)gy < H2D && (unsigned)gx < H2D)
      v = h2[(size_t)c * H2D * H2D + (size_t)gy * H2D + gx];
    hs[c][r][cc] = v;
  }
  __syncthreads();
  {
    const int r = tid >> 3;
    const int c4 = (tid & 7) << 2;
    float acc[2][4];
    #pragma unroll
    for (int oc = 0; oc < 2; ++oc)
      #pragma unroll
      for (int j = 0; j < 4; ++j) acc[oc][j] = B3[oc];
    #pragma unroll
    for (int ic = 0; ic < 2; ++ic) {
      float xr[3][8];
      #pragma unroll
      for (int dy = 0; dy < 3; ++dy) {
        const float4 q0 = *(const float4*)&hs[ic][r + dy][c4];
        const float4 q1 = *(const float4*)&hs[ic][r + dy][c4 + 4];
        xr[dy][0] = q0.x; xr[dy][1] = q0.y; xr[dy][2] = q0.z; xr[dy][3] = q0.w;
        xr[dy][4] = q1.x; xr[dy][5] = q1.y; xr[dy][6] = q1.z; xr[dy][7] = q1.w;
      }
      #pragma unroll
      for (int oc = 0; oc < 2; ++oc)
        #pragma unroll
        for (int dy = 0; dy < 3; ++dy)
          #pragma unroll
          for (int dx = 0; dx < 3; ++dx) {
            const float w = W3[oc * 18 + ic * 9 + dy * 3 + dx];
            #pragma unroll
            for (int j = 0; j < 4; ++j) acc[oc][j] += xr[dy][j + dx] * w;
          }
    }
    const int gy = by * 30 - 1 + r;
    const bool rOK = (unsigned)gy < H2D;
    const int gxb = bx * 30 - 1 + c4;
    #pragma unroll
    for (int oc = 0; oc < 2; ++oc) {
      float4 o;
      o.x = (rOK && (unsigned)(gxb + 0) < H2D) ? acc[oc][0] : 0.f;
      o.y = (rOK && (unsigned)(gxb + 1) < H2D) ? acc[oc][1] : 0.f;
      o.z = (rOK && (unsigned)(gxb + 2) < H2D) ? acc[oc][2] : 0.f;
      o.w = (rOK && (unsigned)(gxb + 3) < H2D) ? acc[oc][3] : 0.f;
      *(float4*)&c3s[oc][r][c4] = o;
    }
  }
  __syncthreads();
  float W4[18], B4;
  #pragma unroll
  for (int i = 0; i < 18; ++i) W4[i] = w4[i];
  B4 = b4[0];
  const int ty = tid >> 4, tx = tid & 15;
  if (ty < 15 && tx < 15) {
    float cr[2][4][4];
    #pragma unroll
    for (int ic = 0; ic < 2; ++ic)
      #pragma unroll
      for (int rr = 0; rr < 4; ++rr) {
        const float2 p0 = *(const float2*)&c3s[ic][2 * ty + rr][2 * tx];
        const float2 p1 = *(const float2*)&c3s[ic][2 * ty + rr][2 * tx + 2];
        cr[ic][rr][0] = p0.x; cr[ic][rr][1] = p0.y;
        cr[ic][rr][2] = p1.x; cr[ic][rr][3] = p1.y;
      }
    float m = -INFINITY;
    #pragma unroll
    for (int sy = 0; sy < 2; ++sy)
      #pragma unroll
      for (int sx = 0; sx < 2; ++sx) {
        float a = B4;
        #pragma unroll
        for (int ic = 0; ic < 2; ++ic)
          #pragma unroll
          for (int dy = 0; dy < 3; ++dy)
            #pragma unroll
            for (int dx = 0; dx < 3; ++dx)
              a += cr[ic][sy + dy][sx + dx] * W4[ic * 9 + dy * 3 + dx];
        m = fmaxf(m, a);
      }
    red[(size_t)(by * 15 + ty) * FMD + (bx * 15 + tx)] = m;
  }
}

// ============ K3: rpn_conv (50x50, stride 50)  (reduced -> y [2,21,21]) ============
__global__ __launch_bounds__(256) void k3_rpnconv(
    const float* __restrict__ red,
    const float* __restrict__ w, const float* __restrict__ b,
    float* __restrict__ y) {
  __shared__ float part[256];
  const int cell = blockIdx.x;
  const int i = cell / FF, j = cell % FF;
  const int tid = threadIdx.x;
  float a0 = 0.f, a1 = 0.f;
  for (int t = tid; t < 2500; t += 256) {
    int ay = t / 50, ax = t % 50;
    float v = red[(size_t)(50 * i + ay) * FMD + 50 * j + ax];
    a0 += v * w[t];
    a1 += v * w[2500 + t];
  }
  part[tid] = a0;
  __syncthreads();
  for (int s = 128; s > 0; s >>= 1) {
    if (tid < s) part[tid] += part[tid + s];
    __syncthreads();
  }
  if (tid == 0) y[cell] = part[0] + b[0];
  __syncthreads();
  part[tid] = a1;
  __syncthreads();
  for (int s = 128; s > 0; s >>= 1) {
    if (tid < s) part[tid] += part[tid + s];
    __syncthreads();
  }
  if (tid == 0) y[441 + cell] = part[0] + b[1];
}

// ============ K4: rpn heads + faithful masked-select + proposals/rects ============
__global__ __launch_bounds__(512) void k4_select(
    const float* __restrict__ y,
    const float* __restrict__ bbw, const float* __restrict__ bbb,
    const float* __restrict__ clw, const float* __restrict__ clb,
    float* __restrict__ props_out, int* __restrict__ rects,
    unsigned* __restrict__ pooled_m) {
  __shared__ float ys[2][23][23];
  __shared__ unsigned char flag[6][441];
  __shared__ short pos[6][20];
  __shared__ int cnt[6];
  __shared__ int selT[20];
  __shared__ float offv[20], anchv[20];
  const int tid = threadIdx.x;
  for (int l = tid; l < 2 * 23 * 23; l += 512) ((float*)ys)[l] = 0.f;
  __syncthreads();
  for (int l = tid; l < 2 * 441; l += 512) {
    int c = l / 441, p = l % 441;
    ys[c][p / 21 + 1][p % 21 + 1] = y[l];
  }
  __syncthreads();
  for (int l = tid; l < 6 * 441; l += 512) {
    int a = l / 441, p = l % 441, i = p / 21, j = p % 21;
    float v = clb[a];
    #pragma unroll
    for (int c2 = 0; c2 < 2; c2++)
      #pragma unroll
      for (int dy = 0; dy < 3; dy++)
        #pragma unroll
        for (int dx = 0; dx < 3; dx++)
          v += ys[c2][i + dy][j + dx] * clw[a * 18 + c2 * 9 + dy * 3 + dx];
    flag[a][p] = (tanhf(v) > 0.95f) ? 1 : 0;
  }
  __syncthreads();
  if (tid < 6) {
    int c = 0;
    for (int p = 0; p < 441; p++)
      if (flag[tid][p]) {
        if (c < 20) pos[tid][c] = (short)p;
        c++;
      }
    cnt[tid] = c;
  }
  __syncthreads();
  if (tid == 0) {
    int s = 0;
    for (int g = 0; g < 24 && s < 20; g++) {
      int a = g >> 2;
      int take = cnt[a] < 20 - s ? cnt[a] : 20 - s;
      for (int r = 0; r < take; r++) selT[s++] = g * 441 + (int)pos[a][r];
    }
    if (s < 20) {
      for (int t = 0; t < 10584 && s < 20; t++) {
        int a = t / 1764, p = t % 441;
        if (!flag[a][p]) selT[s++] = t;
      }
    }
  }
  __syncthreads();
  if (tid < 20) {
    int t = selT[tid];
    int ch = t / 441, p = t % 441, i = p / 21, j = p % 21;
    int a = ch >> 2, c = ch & 3;
    float v = bbb[ch];
    #pragma unroll
    for (int c2 = 0; c2 < 2; c2++)
      #pragma unroll
      for (int dy = 0; dy < 3; dy++)
        #pragma unroll
        for (int dx = 0; dx < 3; dx++)
          v += ys[c2][i + dy][j + dx] * bbw[ch * 18 + c2 * 9 + dy * 3 + dx];
    offv[tid] = v;
    float sz = (a < 3) ? 1.f : 2.f;
    int am = a % 3;
    float ar = (am == 0) ? 0.5f : (am == 1 ? 1.f : 2.f);
    float base;
    if (c == 0) base = 0.f;
    else if (c == 1) base = sz * -(ar - 1.f) * 0.5f;
    else if (c == 2) base = sz;
    else base = sz * (1.f + (ar - 1.f) * 0.5f);
    anchv[tid] = base + ((c & 1) ? (float)j : (float)i);
  }
  __syncthreads();
  if (tid < 5) {
    int k = tid;
    float o0 = offv[4 * k], o1 = offv[4 * k + 1], o2 = offv[4 * k + 2], o3 = offv[4 * k + 3];
    float a0 = anchv[4 * k], a2 = anchv[4 * k + 2], a3 = anchv[4 * k + 3];
    float p0 = fminf(fmaxf(o0 + a0 - a2 * 0.5f, 0.f), 21.f) * 50.f;
    float p1 = fminf(fmaxf(o1 - a3 * 0.5f, 0.f), 21.f) * 50.f;
    float p2 = fminf(fmaxf(o2 + a0 + a2 * 0.5f, 0.f), 21.f) * 50.f;
    float p3 = fminf(fmaxf(o3 + a3 * 0.5f, 0.f), 21.f) * 50.f;
    props_out[k * 4 + 0] = p0;
    props_out[k * 4 + 1] = p1;
    props_out[k * 4 + 2] = p2;
    props_out[k * 4 + 3] = p3;
    float x1 = rintf(p0), y1 = rintf(p1), x2 = rintf(p2), y2 = rintf(p3);
    float bwf = fmaxf(x2 - x1 + 1.f, 1.f) * 0.5f;
    float bhf = fmaxf(y2 - y1 + 1.f, 1.f) * 0.5f;
    for (int ph = 0; ph < 2; ph++)
      for (int pw = 0; pw < 2; pw++) {
        int hsv = (int)fminf(fmaxf(floorf((float)ph * bhf) + y1, 0.f), 1080.f);
        int hev = (int)fminf(fmaxf(ceilf((float)(ph + 1) * bhf) + y1, 0.f), 1080.f);
        int wsv = (int)fminf(fmaxf(floorf((float)pw * bwf) + x1, 0.f), 1080.f);
        int wev = (int)fminf(fmaxf(ceilf((float)(pw + 1) * bwf) + x1, 0.f), 1080.f);
        int idx = k * 4 + ph * 2 + pw;
        rects[idx * 4 + 0] = hsv;
        rects[idx * 4 + 1] = hev;
        rects[idx * 4 + 2] = wsv;
        rects[idx * 4 + 3] = wev;
      }
  }
  if (tid >= 32 && tid < 52) pooled_m[tid - 32] = 0x007FFFFFu;  // mapped(-inf)
}

// ============ K5: RoI max pool (atomicMax on order-preserving uint map) ============
__global__ __launch_bounds__(256) void k5_roipool(
    const float* __restrict__ red, const int* __restrict__ rects,
    unsigned* __restrict__ pooled_m) {
  const int cell = blockIdx.x;
  const int hs = rects[cell * 4 + 0], he = rects[cell * 4 + 1];
  const int wss = rects[cell * 4 + 2], wee = rects[cell * 4 + 3];
  const int nr = he - hs;
  if (nr <= 0 || wee <= wss) return;
  const int slice = blockIdx.y, nslice = gridDim.y;
  const int r0 = hs + (int)((long)nr * slice / nslice);
  const int r1 = hs + (int)((long)nr * (slice + 1) / nslice);
  float m = -INFINITY;
  for (int r = r0; r < r1; r++)
    for (int c = wss + (int)threadIdx.x; c < wee; c += 256)
      m = fmaxf(m, red[(size_t)r * FMD + c]);
  __shared__ float part[256];
  part[threadIdx.x] = m;
  __syncthreads();
  for (int s = 128; s > 0; s >>= 1) {
    if ((int)threadIdx.x < s) part[threadIdx.x] = fmaxf(part[threadIdx.x], part[threadIdx.x + s]);
    __syncthreads();
  }
  if (threadIdx.x == 0 && part[0] > -INFINITY) {
    unsigned u = __float_as_uint(part[0]);
    u = (u & 0x80000000u) ? ~u : (u | 0x80000000u);
    atomicMax(&pooled_m[cell], u);
  }
}

// ============ K6: fc / box / cls heads -> d_out (30 floats) ============
__global__ void k6_heads(
    const unsigned* __restrict__ pooled_m, const float* __restrict__ props,
    const float* __restrict__ fcw, const float* __restrict__ fcb,
    const float* __restrict__ bxw, const float* __restrict__ bxb,
    const float* __restrict__ clw, const float* __restrict__ clb,
    float* __restrict__ out) {
  if (threadIdx.x != 0 || blockIdx.x != 0) return;
  float pooled[5][4];
  for (int i = 0; i < 20; i++) {
    unsigned u = pooled_m[i];
    float f = (u & 0x80000000u) ? __uint_as_float(u ^ 0x80000000u) : __uint_as_float(~u);
    if (!isfinite(f)) f = 0.f;
    pooled[i / 4][i % 4] = f;
  }
  for (int k = 0; k < 5; k++) {
    float fc[12];
    for (int m = 0; m < 12; m++) {
      float v = fcb[m];
      for (int n = 0; n < 4; n++) v += pooled[k][n] * fcw[m * 4 + n];
      fc[m] = v;
    }
    float bo[4];
    for (int c = 0; c < 4; c++) {
      float v = bxb[c];
      for (int m = 0; m < 12; m++) v += fc[m] * bxw[c * 12 + m];
      bo[c] = v;
    }
    float p0 = props[k * 4], p1 = props[k * 4 + 1], p2 = props[k * 4 + 2], p3 = props[k * 4 + 3];
    out[k * 4 + 0] = fminf(fmaxf(p0 + bo[0] - bo[2] * 0.5f, 0.f), 3.f);
    out[k * 4 + 1] = fminf(fmaxf(p1 - bo[3] * 0.5f, 0.f), 1.f);
    out[k * 4 + 2] = fminf(fmaxf(p2 + bo[0] + bo[2] * 0.5f, 0.f), 3.f);
    out[k * 4 + 3] = fminf(fmaxf(p3 + bo[3] * 0.5f, 0.f), 1.f);
    float l0 = clb[0], l1 = clb[1];
    for (int m = 0; m < 12; m++) {
      l0 += fc[m] * clw[m];
      l1 += fc[m] * clw[12 + m];
    }
    float mx = fmaxf(l0, l1);
    float e0 = expf(l0 - mx), e1 = expf(l1 - mx);
    out[20 + k * 2 + 0] = e0 / (e0 + e1);
    out[20 + k * 2 + 1] = e1 / (e0 + e1);
  }
}

extern "C" void kernel_launch(void* const* d_in, const int* in_sizes, int n_in,
                              void* d_out, int out_size, void* d_ws, size_t ws_size,
                              hipStream_t stream) {
  const float* x   = (const float*)d_in[0];
  const float* w1  = (const float*)d_in[1];
  const float* b1  = (const float*)d_in[2];
  const float* w2  = (const float*)d_in[3];
  const float* b2  = (const float*)d_in[4];
  const float* w3  = (const float*)d_in[5];
  const float* b3  = (const float*)d_in[6];
  const float* w4  = (const float*)d_in[7];
  const float* b4  = (const float*)d_in[8];
  const float* rw  = (const float*)d_in[9];
  const float* rb  = (const float*)d_in[10];
  const float* bbw = (const float*)d_in[11];
  const float* bbb = (const float*)d_in[12];
  const float* clw = (const float*)d_in[13];
  const float* clb = (const float*)d_in[14];
  const float* fcw = (const float*)d_in[15];
  const float* fcb = (const float*)d_in[16];
  const float* bxw = (const float*)d_in[17];
  const float* bxb = (const float*)d_in[18];
  const float* c2w = (const float*)d_in[19];
  const float* c2b = (const float*)d_in[20];

  char* wsb = (char*)d_ws;

  if (ws_size >= 160000000ull) {
    // split path: c1(bf16) 0..111,974,400 | h2 | red | small; c3 aliases c1
    u16*   c1u = (u16*)wsb;
    float* h2  = (float*)(wsb + 111974400);
    float* c3  = (float*)wsb;
    float* red = (float*)(wsb + 149299200);
    float* yv  = (float*)(wsb + 153964800);
    float* props = yv + 882;
    int*   rects = (int*)(props + 20);
    unsigned* pooled_m = (unsigned*)(rects + 80);

    k_conv1    <<<4557, 256, 0, stream>>>(x, w1, b1, c1u);
    k_conv2pool<<<4557, 256, 0, stream>>>(c1u, w2, b2, h2);
    k_conv3    <<<1140, 256, 0, stream>>>(h2, w3, b3, c3);
    k_conv4pool<<<1140, 256, 0, stream>>>(c3, w4, b4, red);
    k3_rpnconv<<<441, 256, 0, stream>>>(red, rw, rb, yv);
    k4_select<<<1, 512, 0, stream>>>(yv, bbw, bbb, clw, clb, props, rects, pooled_m);
    k5_roipool<<<dim3(20, 16), 256, 0, stream>>>(red, rects, pooled_m);
    k6_heads<<<1, 64, 0, stream>>>(pooled_m, props, fcw, fcb, bxw, bxb, c2w, c2b,
                                   (float*)d_out);
  } else {
    // fallback: round-2 fused path (42 MB workspace)
    float* ws = (float*)d_ws;
    float* h2 = ws;
    float* red = ws + 9331200;
    float* yv = ws + 10497600;
    float* props = ws + 10498482;
    int* rects = (int*)(ws + 10498502);
    unsigned* pooled_m = (unsigned*)(ws + 10498582);

    k1_backbone1<<<dim3(144, 144), 256, 0, stream>>>(x, w1, b1, w2, b2, h2);
    k2_backbone2<<<dim3(72, 72), 256, 0, stream>>>(h2, w3, b3, w4, b4, red);
    k3_rpnconv<<<441, 256, 0, stream>>>(red, rw, rb, yv);
    k4_select<<<1, 512, 0, stream>>>(yv, bbw, bbb, clw, clb, props, rects, pooled_m);
    k5_roipool<<<dim3(20, 16), 256, 0, stream>>>(red, rects, pooled_m);
    k6_heads<<<1, 64, 0, stream>>>(pooled_m, props, fcw, fcb, bxw, bxb, c2w, c2b,
                                   (float*)d_out);
  }
}

// Round 9
// 222.709 us; speedup vs baseline: 1.9355x; 1.0084x over previous
//
#include <hip/hip_runtime.h>
#include <math.h>

#define IMG 4320
#define H2D 2160
#define FMD 1080
#define FF 21

typedef unsigned short u16;

__device__ __forceinline__ float bf2f(u16 h) {
  return __uint_as_float(((unsigned)h) << 16);
}
__device__ __forceinline__ u16 f2bf(float f) {  // RTNE
  unsigned u = __float_as_uint(f);
  unsigned r = 0x7FFFu + ((u >> 16) & 1u);
  return (u16)((u + r) >> 16);
}

// ============================================================================
// Stage 1a: conv1 (x fp32 -> c1 bf16), 4 rows x 4 cols per thread, batched
// branch-free loads, VGPR cap 256.  (unchanged from round 8 = control)
// ============================================================================
template<bool REDGE>
__device__ __forceinline__ void conv1_body(
    const int gx, const int gy,
    const float* __restrict__ x, const float* __restrict__ w1,
    const float* __restrict__ b1, u16* __restrict__ c1) {
  const int c0 = gx * 4, r0 = gy * 4;
  const bool okL = gx > 0, okR = gx < 1079;
  float s[6][3][6];
  #pragma unroll
  for (int rr = 0; rr < 6; ++rr) {
    const int row = r0 - 1 + rr;
    const int rowc = REDGE ? (row < 0 ? 0 : (row > IMG - 1 ? IMG - 1 : row)) : row;
    const size_t rbase = (size_t)rowc * IMG + c0;
    #pragma unroll
    for (int ic = 0; ic < 3; ++ic) {
      const float* bp = x + (size_t)ic * IMG * IMG + rbase;
      const float4 q = *(const float4*)bp;
      s[rr][ic][1] = q.x; s[rr][ic][2] = q.y; s[rr][ic][3] = q.z; s[rr][ic][4] = q.w;
      s[rr][ic][0] = bp[okL ? -1 : 0];
      s[rr][ic][5] = bp[okR ? 4 : 0];
    }
  }
  #pragma unroll
  for (int rr = 0; rr < 6; ++rr) {
    const bool rok = REDGE ? ((unsigned)(r0 - 1 + rr) < (unsigned)IMG) : true;
    #pragma unroll
    for (int ic = 0; ic < 3; ++ic) {
      if (REDGE) {
        #pragma unroll
        for (int j = 0; j < 6; ++j) s[rr][ic][j] = rok ? s[rr][ic][j] : 0.f;
      }
      s[rr][ic][0] = okL ? s[rr][ic][0] : 0.f;
      s[rr][ic][5] = okR ? s[rr][ic][5] : 0.f;
    }
  }
  float acc[3][4][4];
  #pragma unroll
  for (int oc = 0; oc < 3; ++oc) {
    const float bb = b1[oc];
    #pragma unroll
    for (int r = 0; r < 4; ++r)
      #pragma unroll
      for (int j = 0; j < 4; ++j) acc[oc][r][j] = bb;
  }
  #pragma unroll
  for (int oc = 0; oc < 3; ++oc)
    #pragma unroll
    for (int ic = 0; ic < 3; ++ic)
      #pragma unroll
      for (int dy = 0; dy < 3; ++dy)
        #pragma unroll
        for (int dx = 0; dx < 3; ++dx) {
          const float w = w1[oc * 27 + ic * 9 + dy * 3 + dx];
          #pragma unroll
          for (int r = 0; r < 4; ++r)
            #pragma unroll
            for (int j = 0; j < 4; ++j)
              acc[oc][r][j] += s[r + dy][ic][j + dx] * w;
        }
  #pragma unroll
  for (int oc = 0; oc < 3; ++oc)
    #pragma unroll
    for (int r = 0; r < 4; ++r) {
      ushort4 h;
      h.x = f2bf(acc[oc][r][0]); h.y = f2bf(acc[oc][r][1]);
      h.z = f2bf(acc[oc][r][2]); h.w = f2bf(acc[oc][r][3]);
      *(ushort4*)(c1 + (size_t)oc * IMG * IMG + (size_t)(r0 + r) * IMG + c0) = h;
    }
}

__global__ __launch_bounds__(256, 2) void k_conv1(
    const float* __restrict__ x, const float* __restrict__ w1,
    const float* __restrict__ b1, u16* __restrict__ c1) {
  const int g = blockIdx.x * 256 + threadIdx.x;
  if (g >= 1080 * 1080) return;
  const int gx = g % 1080, gy = g / 1080;
  const int gy_min = (blockIdx.x * 256) / 1080;
  const int gy_max = (blockIdx.x * 256 + 255) / 1080;
  if (gy_min == 0 || gy_max >= 1079) conv1_body<true>(gx, gy, x, w1, b1, c1);
  else                               conv1_body<false>(gx, gy, x, w1, b1, c1);
}

// ============================================================================
// Stage 1b: conv2 + 2x2 maxpool (c1 bf16 -> h2 fp32 [2,2160,2160])
// NEW: 2 pooled rows x 4 pooled cols per thread (4 conv rows x 8 conv cols,
// window 6x10), interior loads all ushort4, one float4 store per row.
// ============================================================================
template<bool REDGE>
__device__ __forceinline__ void conv2_body(
    const int gx, const int gy,
    const u16* __restrict__ c1, const float* __restrict__ w2,
    const float* __restrict__ b2, float* __restrict__ h2) {
  const int c0 = gx * 8, r0 = gy * 4;
  const bool okL = gx > 0, okR = gx < 539;
  ushort4 q0v[6][3], q1v[6][3];
  u16 hl[6][3], hr[6][3];
  #pragma unroll
  for (int rr = 0; rr < 6; ++rr) {
    const int row = r0 - 1 + rr;
    const int rowc = REDGE ? (row < 0 ? 0 : (row > IMG - 1 ? IMG - 1 : row)) : row;
    const size_t rbase = (size_t)rowc * IMG + c0;
    #pragma unroll
    for (int ic = 0; ic < 3; ++ic) {
      const u16* bp = c1 + (size_t)ic * IMG * IMG + rbase;
      q0v[rr][ic] = *(const ushort4*)bp;
      q1v[rr][ic] = *(const ushort4*)(bp + 4);
      hl[rr][ic] = bp[okL ? -1 : 0];
      hr[rr][ic] = bp[okR ? 8 : 0];
    }
  }
  float s[6][3][10];
  #pragma unroll
  for (int rr = 0; rr < 6; ++rr) {
    const bool rok = REDGE ? ((unsigned)(r0 - 1 + rr) < (unsigned)IMG) : true;
    #pragma unroll
    for (int ic = 0; ic < 3; ++ic) {
      s[rr][ic][0] = (okL && rok) ? bf2f(hl[rr][ic]) : 0.f;
      s[rr][ic][1] = bf2f(q0v[rr][ic].x);
      s[rr][ic][2] = bf2f(q0v[rr][ic].y);
      s[rr][ic][3] = bf2f(q0v[rr][ic].z);
      s[rr][ic][4] = bf2f(q0v[rr][ic].w);
      s[rr][ic][5] = bf2f(q1v[rr][ic].x);
      s[rr][ic][6] = bf2f(q1v[rr][ic].y);
      s[rr][ic][7] = bf2f(q1v[rr][ic].z);
      s[rr][ic][8] = bf2f(q1v[rr][ic].w);
      s[rr][ic][9] = (okR && rok) ? bf2f(hr[rr][ic]) : 0.f;
      if (REDGE) {
        #pragma unroll
        for (int j = 1; j < 9; ++j) s[rr][ic][j] = rok ? s[rr][ic][j] : 0.f;
      }
    }
  }
  float pm[2][2][4];
  #pragma unroll
  for (int oc = 0; oc < 2; ++oc)
    #pragma unroll
    for (int a = 0; a < 2; ++a)
      #pragma unroll
      for (int b = 0; b < 4; ++b) pm[oc][a][b] = -INFINITY;
  #pragma unroll
  for (int cr = 0; cr < 4; ++cr) {
    float v[2][8];
    #pragma unroll
    for (int oc = 0; oc < 2; ++oc) {
      const float bb = b2[oc];
      #pragma unroll
      for (int cc = 0; cc < 8; ++cc) v[oc][cc] = bb;
    }
    #pragma unroll
    for (int oc = 0; oc < 2; ++oc)
      #pragma unroll
      for (int ic = 0; ic < 3; ++ic)
        #pragma unroll
        for (int dy = 0; dy < 3; ++dy)
          #pragma unroll
          for (int dx = 0; dx < 3; ++dx) {
            const float w = w2[oc * 27 + ic * 9 + dy * 3 + dx];
            #pragma unroll
            for (int cc = 0; cc < 8; ++cc)
              v[oc][cc] += s[cr + dy][ic][cc + dx] * w;
          }
    #pragma unroll
    for (int oc = 0; oc < 2; ++oc)
      #pragma unroll
      for (int cc = 0; cc < 8; ++cc)
        pm[oc][cr >> 1][cc >> 1] = fmaxf(pm[oc][cr >> 1][cc >> 1], v[oc][cc]);
  }
  #pragma unroll
  for (int oc = 0; oc < 2; ++oc)
    #pragma unroll
    for (int rp = 0; rp < 2; ++rp) {
      float4 o;
      o.x = pm[oc][rp][0]; o.y = pm[oc][rp][1];
      o.z = pm[oc][rp][2]; o.w = pm[oc][rp][3];
      *(float4*)(h2 + (size_t)oc * H2D * H2D + (size_t)(gy * 2 + rp) * H2D + gx * 4) = o;
    }
}

__global__ __launch_bounds__(256, 2) void k_conv2pool(
    const u16* __restrict__ c1, const float* __restrict__ w2,
    const float* __restrict__ b2, float* __restrict__ h2) {
  const int g = blockIdx.x * 256 + threadIdx.x;
  if (g >= 540 * 1080) return;
  const int gx = g % 540, gy = g / 540;
  const int gy_min = (blockIdx.x * 256) / 540;
  const int gy_max = (blockIdx.x * 256 + 255) / 540;
  if (gy_min == 0 || gy_max >= 1079) conv2_body<true>(gx, gy, c1, w2, b2, h2);
  else                               conv2_body<false>(gx, gy, c1, w2, b2, h2);
}

// ============================================================================
// Stage 2 (FUSED, proven round-2 kernel): conv3 -> conv4 -> maxpool2
// (h2 -> red [1080,1080]) via LDS, grid 72x72, 30x30 region per block.
// ============================================================================
__global__ __launch_bounds__(256) void k2_backbone2(
    const float* __restrict__ h2,
    const float* __restrict__ w3, const float* __restrict__ b3,
    const float* __restrict__ w4, const float* __restrict__ b4,
    float* __restrict__ red) {
  __shared__ float hs[2][34][36];
  __shared__ float c3s[2][32][36];
  const int tid = threadIdx.x;
  const int bx = blockIdx.x, by = blockIdx.y;
  const int gy0 = by * 30 - 2, gx0 = bx * 30 - 2;
  float W3[36], B3[2];
  #pragma unroll
  for (int i = 0; i < 36; ++i) W3[i] = w3[i];
  B3[0] = b3[0]; B3[1] = b3[1];
  for (int l = tid; l < 2 * 34 * 34; l += 256) {
    int c = l / 1156, rem = l % 1156, r = rem / 34, cc = rem % 34;
    int gy = gy0 + r, gx = gx0 + cc;
    float v = 0.f;
    if ((unsigned)gy < H2D && (unsigned)gx < H2D)
      v = h2[(size_t)c * H2D * H2D + (size_t)gy * H2D + gx];
    hs[c][r][cc] = v;
  }
  __syncthreads();
  {
    const int r = tid >> 3;
    const int c4 = (tid & 7) << 2;
    float acc[2][4];
    #pragma unroll
    for (int oc = 0; oc < 2; ++oc)
      #pragma unroll
      for (int j = 0; j < 4; ++j) acc[oc][j] = B3[oc];
    #pragma unroll
    for (int ic = 0; ic < 2; ++ic) {
      float xr[3][8];
      #pragma unroll
      for (int dy = 0; dy < 3; ++dy) {
        const float4 q0 = *(const float4*)&hs[ic][r + dy][c4];
        const float4 q1 = *(const float4*)&hs[ic][r + dy][c4 + 4];
        xr[dy][0] = q0.x; xr[dy][1] = q0.y; xr[dy][2] = q0.z; xr[dy][3] = q0.w;
        xr[dy][4] = q1.x; xr[dy][5] = q1.y; xr[dy][6] = q1.z; xr[dy][7] = q1.w;
      }
      #pragma unroll
      for (int oc = 0; oc < 2; ++oc)
        #pragma unroll
        for (int dy = 0; dy < 3; ++dy)
          #pragma unroll
          for (int dx = 0; dx < 3; ++dx) {
            const float w = W3[oc * 18 + ic * 9 + dy * 3 + dx];
            #pragma unroll
            for (int j = 0; j < 4; ++j) acc[oc][j] += xr[dy][j + dx] * w;
          }
    }
    const int gy = by * 30 - 1 + r;
    const bool rOK = (unsigned)gy < H2D;
    const int gxb = bx * 30 - 1 + c4;
    #pragma unroll
    for (int oc = 0; oc < 2; ++oc) {
      float4 o;
      o.x = (rOK && (unsigned)(gxb + 0) < H2D) ? acc[oc][0] : 0.f;
      o.y = (rOK && (unsigned)(gxb + 1) < H2D) ? acc[oc][1] : 0.f;
      o.z = (rOK && (unsigned)(gxb + 2) < H2D) ? acc[oc][2] : 0.f;
      o.w = (rOK && (unsigned)(gxb + 3) < H2D) ? acc[oc][3] : 0.f;
      *(float4*)&c3s[oc][r][c4] = o;
    }
  }
  __syncthreads();
  float W4[18], B4;
  #pragma unroll
  for (int i = 0; i < 18; ++i) W4[i] = w4[i];
  B4 = b4[0];
  const int ty = tid >> 4, tx = tid & 15;
  if (ty < 15 && tx < 15) {
    float cr[2][4][4];
    #pragma unroll
    for (int ic = 0; ic < 2; ++ic)
      #pragma unroll
      for (int rr = 0; rr < 4; ++rr) {
        const float2 p0 = *(const float2*)&c3s[ic][2 * ty + rr][2 * tx];
        const float2 p1 = *(const float2*)&c3s[ic][2 * ty + rr][2 * tx + 2];
        cr[ic][rr][0] = p0.x; cr[ic][rr][1] = p0.y;
        cr[ic][rr][2] = p1.x; cr[ic][rr][3] = p1.y;
      }
    float m = -INFINITY;
    #pragma unroll
    for (int sy = 0; sy < 2; ++sy)
      #pragma unroll
      for (int sx = 0; sx < 2; ++sx) {
        float a = B4;
        #pragma unroll
        for (int ic = 0; ic < 2; ++ic)
          #pragma unroll
          for (int dy = 0; dy < 3; ++dy)
            #pragma unroll
            for (int dx = 0; dx < 3; ++dx)
              a += cr[ic][sy + dy][sx + dx] * W4[ic * 9 + dy * 3 + dx];
        m = fmaxf(m, a);
      }
    red[(size_t)(by * 15 + ty) * FMD + (bx * 15 + tx)] = m;
  }
}

// ============ fallback stage-1 fused kernel (small-ws path) ============
__global__ __launch_bounds__(256) void k1_backbone1(
    const float* __restrict__ x,
    const float* __restrict__ w1, const float* __restrict__ b1,
    const float* __restrict__ w2, const float* __restrict__ b2,
    float* __restrict__ h2) {
  __shared__ float xs[3][34][36];
  __shared__ float c1s[3][32][36];
  const int tid = threadIdx.x;
  const int bx = blockIdx.x, by = blockIdx.y;
  const int gy0 = by * 30 - 2, gx0 = bx * 30 - 2;
  float W1[81], B1[3];
  #pragma unroll
  for (int i = 0; i < 81; ++i) W1[i] = w1[i];
  #pragma unroll
  for (int i = 0; i < 3; ++i) B1[i] = b1[i];
  for (int l = tid; l < 3 * 34 * 34; l += 256) {
    int c = l / 1156, rem = l % 1156, r = rem / 34, cc = rem % 34;
    int gy = gy0 + r, gx = gx0 + cc;
    float v = 0.f;
    if ((unsigned)gy < IMG && (unsigned)gx < IMG)
      v = x[(size_t)c * IMG * IMG + (size_t)gy * IMG + gx];
    xs[c][r][cc] = v;
  }
  __syncthreads();
  {
    const int r = tid >> 3;
    const int c4 = (tid & 7) << 2;
    float acc[3][4];
    #pragma unroll
    for (int oc = 0; oc < 3; ++oc)
      #pragma unroll
      for (int j = 0; j < 4; ++j) acc[oc][j] = B1[oc];
    #pragma unroll
    for (int ic = 0; ic < 3; ++ic) {
      float xr[3][8];
      #pragma unroll
      for (int dy = 0; dy < 3; ++dy) {
        const float4 q0 = *(const float4*)&xs[ic][r + dy][c4];
        const float4 q1 = *(const float4*)&xs[ic][r + dy][c4 + 4];
        xr[dy][0] = q0.x; xr[dy][1] = q0.y; xr[dy][2] = q0.z; xr[dy][3] = q0.w;
        xr[dy][4] = q1.x; xr[dy][5] = q1.y; xr[dy][6] = q1.z; xr[dy][7] = q1.w;
      }
      #pragma unroll
      for (int oc = 0; oc < 3; ++oc)
        #pragma unroll
        for (int dy = 0; dy < 3; ++dy)
          #pragma unroll
          for (int dx = 0; dx < 3; ++dx) {
            const float w = W1[oc * 27 + ic * 9 + dy * 3 + dx];
            #pragma unroll
            for (int j = 0; j < 4; ++j) acc[oc][j] += xr[dy][j + dx] * w;
          }
    }
    const int gy = by * 30 - 1 + r;
    const bool rOK = (unsigned)gy < IMG;
    const int gxb = bx * 30 - 1 + c4;
    #pragma unroll
    for (int oc = 0; oc < 3; ++oc) {
      float4 o;
      o.x = (rOK && (unsigned)(gxb + 0) < IMG) ? acc[oc][0] : 0.f;
      o.y = (rOK && (unsigned)(gxb + 1) < IMG) ? acc[oc][1] : 0.f;
      o.z = (rOK && (unsigned)(gxb + 2) < IMG) ? acc[oc][2] : 0.f;
      o.w = (rOK && (unsigned)(gxb + 3) < IMG) ? acc[oc][3] : 0.f;
      *(float4*)&c1s[oc][r][c4] = o;
    }
  }
  __syncthreads();
  float W2[54], B2[2];
  #pragma unroll
  for (int i = 0; i < 54; ++i) W2[i] = w2[i];
  B2[0] = b2[0]; B2[1] = b2[1];
  const int ty = tid >> 4, tx = tid & 15;
  if (ty < 15 && tx < 15) {
    float cr[3][4][4];
    #pragma unroll
    for (int ic = 0; ic < 3; ++ic)
      #pragma unroll
      for (int rr = 0; rr < 4; ++rr) {
        const float2 p0 = *(const float2*)&c1s[ic][2 * ty + rr][2 * tx];
        const float2 p1 = *(const float2*)&c1s[ic][2 * ty + rr][2 * tx + 2];
        cr[ic][rr][0] = p0.x; cr[ic][rr][1] = p0.y;
        cr[ic][rr][2] = p1.x; cr[ic][rr][3] = p1.y;
      }
    float m0 = -INFINITY, m1 = -INFINITY;
    #pragma unroll
    for (int sy = 0; sy < 2; ++sy)
      #pragma unroll
      for (int sx = 0; sx < 2; ++sx) {
        float a0 = B2[0], a1 = B2[1];
        #pragma unroll
        for (int ic = 0; ic < 3; ++ic)
          #pragma unroll
          for (int dy = 0; dy < 3; ++dy)
            #pragma unroll
            for (int dx = 0; dx < 3; ++dx) {
              const float v = cr[ic][sy + dy][sx + dx];
              a0 += v * W2[ic * 9 + dy * 3 + dx];
              a1 += v * W2[27 + ic * 9 + dy * 3 + dx];
            }
        m0 = fmaxf(m0, a0);
        m1 = fmaxf(m1, a1);
      }
    const size_t o = (size_t)(by * 15 + ty) * H2D + (bx * 15 + tx);
    h2[o] = m0;
    h2[(size_t)H2D * H2D + o] = m1;
  }
}

// ============ K3: rpn_conv (50x50, stride 50)  (reduced -> y [2,21,21]) ============
__global__ __launch_bounds__(256) void k3_rpnconv(
    const float* __restrict__ red,
    const float* __restrict__ w, const float* __restrict__ b,
    float* __restrict__ y) {
  __shared__ float part[256];
  const int cell = blockIdx.x;
  const int i = cell / FF, j = cell % FF;
  const int tid = threadIdx.x;
  float a0 = 0.f, a1 = 0.f;
  for (int t = tid; t < 2500; t += 256) {
    int ay = t / 50, ax = t % 50;
    float v = red[(size_t)(50 * i + ay) * FMD + 50 * j + ax];
    a0 += v * w[t];
    a1 += v * w[2500 + t];
  }
  part[tid] = a0;
  __syncthreads();
  for (int s = 128; s > 0; s >>= 1) {
    if (tid < s) part[tid] += part[tid + s];
    __syncthreads();
  }
  if (tid == 0) y[cell] = part[0] + b[0];
  __syncthreads();
  part[tid] = a1;
  __syncthreads();
  for (int s = 128; s > 0; s >>= 1) {
    if (tid < s) part[tid] += part[tid + s];
    __syncthreads();
  }
  if (tid == 0) y[441 + cell] = part[0] + b[1];
}

// ============ K4: rpn heads + faithful masked-select + proposals/rects ============
__global__ __launch_bounds__(512) void k4_select(
    const float* __restrict__ y,
    const float* __restrict__ bbw, const float* __restrict__ bbb,
    const float* __restrict__ clw, const float* __restrict__ clb,
    float* __restrict__ props_out, int* __restrict__ rects,
    unsigned* __restrict__ pooled_m) {
  __shared__ float ys[2][23][23];
  __shared__ unsigned char flag[6][441];
  __shared__ short pos[6][20];
  __shared__ int cnt[6];
  __shared__ int selT[20];
  __shared__ float offv[20], anchv[20];
  const int tid = threadIdx.x;
  for (int l = tid; l < 2 * 23 * 23; l += 512) ((float*)ys)[l] = 0.f;
  __syncthreads();
  for (int l = tid; l < 2 * 441; l += 512) {
    int c = l / 441, p = l % 441;
    ys[c][p / 21 + 1][p % 21 + 1] = y[l];
  }
  __syncthreads();
  for (int l = tid; l < 6 * 441; l += 512) {
    int a = l / 441, p = l % 441, i = p / 21, j = p % 21;
    float v = clb[a];
    #pragma unroll
    for (int c2 = 0; c2 < 2; c2++)
      #pragma unroll
      for (int dy = 0; dy < 3; dy++)
        #pragma unroll
        for (int dx = 0; dx < 3; dx++)
          v += ys[c2][i + dy][j + dx] * clw[a * 18 + c2 * 9 + dy * 3 + dx];
    flag[a][p] = (tanhf(v) > 0.95f) ? 1 : 0;
  }
  __syncthreads();
  if (tid < 6) {
    int c = 0;
    for (int p = 0; p < 441; p++)
      if (flag[tid][p]) {
        if (c < 20) pos[tid][c] = (short)p;
        c++;
      }
    cnt[tid] = c;
  }
  __syncthreads();
  if (tid == 0) {
    int s = 0;
    for (int g = 0; g < 24 && s < 20; g++) {
      int a = g >> 2;
      int take = cnt[a] < 20 - s ? cnt[a] : 20 - s;
      for (int r = 0; r < take; r++) selT[s++] = g * 441 + (int)pos[a][r];
    }
    if (s < 20) {
      for (int t = 0; t < 10584 && s < 20; t++) {
        int a = t / 1764, p = t % 441;
        if (!flag[a][p]) selT[s++] = t;
      }
    }
  }
  __syncthreads();
  if (tid < 20) {
    int t = selT[tid];
    int ch = t / 441, p = t % 441, i = p / 21, j = p % 21;
    int a = ch >> 2, c = ch & 3;
    float v = bbb[ch];
    #pragma unroll
    for (int c2 = 0; c2 < 2; c2++)
      #pragma unroll
      for (int dy = 0; dy < 3; dy++)
        #pragma unroll
        for (int dx = 0; dx < 3; dx++)
          v += ys[c2][i + dy][j + dx] * bbw[ch * 18 + c2 * 9 + dy * 3 + dx];
    offv[tid] = v;
    float sz = (a < 3) ? 1.f : 2.f;
    int am = a % 3;
    float ar = (am == 0) ? 0.5f : (am == 1 ? 1.f : 2.f);
    float base;
    if (c == 0) base = 0.f;
    else if (c == 1) base = sz * -(ar - 1.f) * 0.5f;
    else if (c == 2) base = sz;
    else base = sz * (1.f + (ar - 1.f) * 0.5f);
    anchv[tid] = base + ((c & 1) ? (float)j : (float)i);
  }
  __syncthreads();
  if (tid < 5) {
    int k = tid;
    float o0 = offv[4 * k], o1 = offv[4 * k + 1], o2 = offv[4 * k + 2], o3 = offv[4 * k + 3];
    float a0 = anchv[4 * k], a2 = anchv[4 * k + 2], a3 = anchv[4 * k + 3];
    float p0 = fminf(fmaxf(o0 + a0 - a2 * 0.5f, 0.f), 21.f) * 50.f;
    float p1 = fminf(fmaxf(o1 - a3 * 0.5f, 0.f), 21.f) * 50.f;
    float p2 = fminf(fmaxf(o2 + a0 + a2 * 0.5f, 0.f), 21.f) * 50.f;
    float p3 = fminf(fmaxf(o3 + a3 * 0.5f, 0.f), 21.f) * 50.f;
    props_out[k * 4 + 0] = p0;
    props_out[k * 4 + 1] = p1;
    props_out[k * 4 + 2] = p2;
    props_out[k * 4 + 3] = p3;
    float x1 = rintf(p0), y1 = rintf(p1), x2 = rintf(p2), y2 = rintf(p3);
    float bwf = fmaxf(x2 - x1 + 1.f, 1.f) * 0.5f;
    float bhf = fmaxf(y2 - y1 + 1.f, 1.f) * 0.5f;
    for (int ph = 0; ph < 2; ph++)
      for (int pw = 0; pw < 2; pw++) {
        int hsv = (int)fminf(fmaxf(floorf((float)ph * bhf) + y1, 0.f), 1080.f);
        int hev = (int)fminf(fmaxf(ceilf((float)(ph + 1) * bhf) + y1, 0.f), 1080.f);
        int wsv = (int)fminf(fmaxf(floorf((float)pw * bwf) + x1, 0.f), 1080.f);
        int wev = (int)fminf(fmaxf(ceilf((float)(pw + 1) * bwf) + x1, 0.f), 1080.f);
        int idx = k * 4 + ph * 2 + pw;
        rects[idx * 4 + 0] = hsv;
        rects[idx * 4 + 1] = hev;
        rects[idx * 4 + 2] = wsv;
        rects[idx * 4 + 3] = wev;
      }
  }
  if (tid >= 32 && tid < 52) pooled_m[tid - 32] = 0x007FFFFFu;  // mapped(-inf)
}

// ============ K5: RoI max pool (atomicMax on order-preserving uint map) ============
__global__ __launch_bounds__(256) void k5_roipool(
    const float* __restrict__ red, const int* __restrict__ rects,
    unsigned* __restrict__ pooled_m) {
  const int cell = blockIdx.x;
  const int hs = rects[cell * 4 + 0], he = rects[cell * 4 + 1];
  const int wss = rects[cell * 4 + 2], wee = rects[cell * 4 + 3];
  const int nr = he - hs;
  if (nr <= 0 || wee <= wss) return;
  const int slice = blockIdx.y, nslice = gridDim.y;
  const int r0 = hs + (int)((long)nr * slice / nslice);
  const int r1 = hs + (int)((long)nr * (slice + 1) / nslice);
  float m = -INFINITY;
  for (int r = r0; r < r1; r++)
    for (int c = wss + (int)threadIdx.x; c < wee; c += 256)
      m = fmaxf(m, red[(size_t)r * FMD + c]);
  __shared__ float part[256];
  part[threadIdx.x] = m;
  __syncthreads();
  for (int s = 128; s > 0; s >>= 1) {
    if ((int)threadIdx.x < s) part[threadIdx.x] = fmaxf(part[threadIdx.x], part[threadIdx.x + s]);
    __syncthreads();
  }
  if (threadIdx.x == 0 && part[0] > -INFINITY) {
    unsigned u = __float_as_uint(part[0]);
    u = (u & 0x80000000u) ? ~u : (u | 0x80000000u);
    atomicMax(&pooled_m[cell], u);
  }
}

// ============ K6: fc / box / cls heads -> d_out (30 floats) ============
__global__ void k6_heads(
    const unsigned* __restrict__ pooled_m, const float* __restrict__ props,
    const float* __restrict__ fcw, const float* __restrict__ fcb,
    const float* __restrict__ bxw, const float* __restrict__ bxb,
    const float* __restrict__ clw, const float* __restrict__ clb,
    float* __restrict__ out) {
  if (threadIdx.x != 0 || blockIdx.x != 0) return;
  float pooled[5][4];
  for (int i = 0; i < 20; i++) {
    unsigned u = pooled_m[i];
    float f = (u & 0x80000000u) ? __uint_as_float(u ^ 0x80000000u) : __uint_as_float(~u);
    if (!isfinite(f)) f = 0.f;
    pooled[i / 4][i % 4] = f;
  }
  for (int k = 0; k < 5; k++) {
    float fc[12];
    for (int m = 0; m < 12; m++) {
      float v = fcb[m];
      for (int n = 0; n < 4; n++) v += pooled[k][n] * fcw[m * 4 + n];
      fc[m] = v;
    }
    float bo[4];
    for (int c = 0; c < 4; c++) {
      float v = bxb[c];
      for (int m = 0; m < 12; m++) v += fc[m] * bxw[c * 12 + m];
      bo[c] = v;
    }
    float p0 = props[k * 4], p1 = props[k * 4 + 1], p2 = props[k * 4 + 2], p3 = props[k * 4 + 3];
    out[k * 4 + 0] = fminf(fmaxf(p0 + bo[0] - bo[2] * 0.5f, 0.f), 3.f);
    out[k * 4 + 1] = fminf(fmaxf(p1 - bo[3] * 0.5f, 0.f), 1.f);
    out[k * 4 + 2] = fminf(fmaxf(p2 + bo[0] + bo[2] * 0.5f, 0.f), 3.f);
    out[k * 4 + 3] = fminf(fmaxf(p3 + bo[3] * 0.5f, 0.f), 1.f);
    float l0 = clb[0], l1 = clb[1];
    for (int m = 0; m < 12; m++) {
      l0 += fc[m] * clw[m];
      l1 += fc[m] * clw[12 + m];
    }
    float mx = fmaxf(l0, l1);
    float e0 = expf(l0 - mx), e1 = expf(l1 - mx);
    out[20 + k * 2 + 0] = e0 / (e0 + e1);
    out[20 + k * 2 + 1] = e1 / (e0 + e1);
  }
}

extern "C" void kernel_launch(void* const* d_in, const int* in_sizes, int n_in,
                              void* d_out, int out_size, void* d_ws, size_t ws_size,
                              hipStream_t stream) {
  const float* x   = (const float*)d_in[0];
  const float* w1  = (const float*)d_in[1];
  const float* b1  = (const float*)d_in[2];
  const float* w2  = (const float*)d_in[3];
  const float* b2  = (const float*)d_in[4];
  const float* w3  = (const float*)d_in[5];
  const float* b3  = (const float*)d_in[6];
  const float* w4  = (const float*)d_in[7];
  const float* b4  = (const float*)d_in[8];
  const float* rw  = (const float*)d_in[9];
  const float* rb  = (const float*)d_in[10];
  const float* bbw = (const float*)d_in[11];
  const float* bbb = (const float*)d_in[12];
  const float* clw = (const float*)d_in[13];
  const float* clb = (const float*)d_in[14];
  const float* fcw = (const float*)d_in[15];
  const float* fcb = (const float*)d_in[16];
  const float* bxw = (const float*)d_in[17];
  const float* bxb = (const float*)d_in[18];
  const float* c2w = (const float*)d_in[19];
  const float* c2b = (const float*)d_in[20];

  char* wsb = (char*)d_ws;

  if (ws_size >= 160000000ull) {
    // split path: c1(bf16) | h2 | red | small
    u16*   c1u = (u16*)wsb;
    float* h2  = (float*)(wsb + 111974400);
    float* red = (float*)(wsb + 149299200);
    float* yv  = (float*)(wsb + 153964800);
    float* props = yv + 882;
    int*   rects = (int*)(props + 20);
    unsigned* pooled_m = (unsigned*)(rects + 80);

    k_conv1    <<<4557, 256, 0, stream>>>(x, w1, b1, c1u);
    k_conv2pool<<<2279, 256, 0, stream>>>(c1u, w2, b2, h2);
    k2_backbone2<<<dim3(72, 72), 256, 0, stream>>>(h2, w3, b3, w4, b4, red);
    k3_rpnconv<<<441, 256, 0, stream>>>(red, rw, rb, yv);
    k4_select<<<1, 512, 0, stream>>>(yv, bbw, bbb, clw, clb, props, rects, pooled_m);
    k5_roipool<<<dim3(20, 16), 256, 0, stream>>>(red, rects, pooled_m);
    k6_heads<<<1, 64, 0, stream>>>(pooled_m, props, fcw, fcb, bxw, bxb, c2w, c2b,
                                   (float*)d_out);
  } else {
    // fallback: round-2 fused path (42 MB workspace)
    float* ws = (float*)d_ws;
    float* h2 = ws;
    float* red = ws + 9331200;
    float* yv = ws + 10497600;
    float* props = ws + 10498482;
    int* rects = (int*)(ws + 10498502);
    unsigned* pooled_m = (unsigned*)(ws + 10498582);

    k1_backbone1<<<dim3(144, 144), 256, 0, stream>>>(x, w1, b1, w2, b2, h2);
    k2_backbone2<<<dim3(72, 72), 256, 0, stream>>>(h2, w3, b3, w4, b4, red);
    k3_rpnconv<<<441, 256, 0, stream>>>(red, rw, rb, yv);
    k4_select<<<1, 512, 0, stream>>>(yv, bbw, bbb, clw, clb, props, rects, pooled_m);
    k5_roipool<<<dim3(20, 16), 256, 0, stream>>>(red, rects, pooled_m);
    k6_heads<<<1, 64, 0, stream>>>(pooled_m, props, fcw, fcb, bxw, bxb, c2w, c2b,
                                   (float*)d_out);
  }
}